// Round 10
// baseline (1992.483 us; speedup 1.0000x reference)
//
#include <hip/hip_runtime.h>

// SelectionGNN clique+line. I/O: float32. Internals: bf16 end-to-end with f32
// accumulation (MFMA + reduce). B=8, N=4096, E=1, K=3, F=[16,32,16],
// MLP 65536->64->1.
// R16: persistent-kernel fusion with HAND-ROLLED device-scope grid barriers
//     (R14's cooperative launch is not graph-capturable; this is).
//     Evidence: R12 (small tile, 2/CU) == R15 (big tile, 1/CU) == ~368 us
//     -> diffuse internals irrelevant; ~200 us of the total is unexplained
//     by kernel work => per-dispatch overhead ~10 us. Collapse 20 dispatches
//     -> 5: memset(ctr) + 4 layer kernels (last one includes MLP head).
//     Co-residency forced: 512 blocks x 72 KB LDS x __launch_bounds__(256,2)
//     = exactly 2 blocks/CU x 256 CU, all resident -> barrier cannot hang.
//     Barrier: agent-scope atomicAdd arrival + coherent poll + __threadfence
//     release/acquire (cross-XCD visibility, G16). Monotonic targets, one
//     u32 counter per kernel, memset once per launch.
//     All phase bodies = R12's verified kernels (only index plumbing).

#define NN 4096
#define BB 8
#define NB 512   // blocks per fused kernel

typedef unsigned short u16;
typedef unsigned int   u32;

typedef __attribute__((ext_vector_type(8))) short bf16x8;  // 8 bf16 = 4 VGPRs
typedef __attribute__((ext_vector_type(4))) float f32x4;

__device__ __forceinline__ u16 f2bf(float f) {
    union { float f; u32 i; } c; c.f = f;
    u32 i = c.i;
    u32 r = (i + 0x7FFFu + ((i >> 16) & 1u)) >> 16;  // RTNE
    return (u16)r;
}
__device__ __forceinline__ float bf2f(u16 u) {
    union { u32 i; float f; } c; c.i = ((u32)u) << 16; return c.f;
}

__device__ __forceinline__ void gload_lds16(const u16* g, u16* l) {
    __builtin_amdgcn_global_load_lds(
        (__attribute__((address_space(1))) void*)g,
        (__attribute__((address_space(3))) void*)l, 16, 0, 0);
}

// ---------------------------------------------------------------------------
// Device-scope grid barrier. All NB blocks co-resident by construction.
// Release: __threadfence (waitcnt + L2 writeback, device scope). Arrival:
// agent-scope atomicAdd. Poll: agent-scope coherent load (no RMW), throttled
// by s_sleep. Acquire: __threadfence (invalidate) after exit.
// Targets are monotonic (tgt = NB * barrier_index) so a single counter per
// kernel serves all barriers with no reset hazard.
// ---------------------------------------------------------------------------
__device__ __forceinline__ void gridbar(u32* ctr, u32 target) {
    __threadfence();
    __syncthreads();
    if (threadIdx.x == 0) {
        __hip_atomic_fetch_add(ctr, 1u, __ATOMIC_RELAXED,
                               __HIP_MEMORY_SCOPE_AGENT);
        while (__hip_atomic_load(ctr, __ATOMIC_RELAXED,
                                 __HIP_MEMORY_SCOPE_AGENT) < target)
            __builtin_amdgcn_s_sleep(8);
    }
    __syncthreads();
    __threadfence();
}

// ---------------------------------------------------------------------------
// Phase: split-K diffusion (R12 structure). 128(M) x 64(N) tile, BK=64.
// LDS: As = L[0..24576) (3 x 8192 u16), Bs = L[24576..36864) (3 x 4096 u16).
// 3-buffer depth-2 pipeline, counted vmcnt(12/6/0) + raw s_barrier.
// ---------------------------------------------------------------------------
template <int ITERS, int MT>
__device__ void dev_diffuse(u16* L, const u16* __restrict__ Z,
                            const u16* __restrict__ S, u16* __restrict__ Part,
                            int ntR, int mtile, int kz)
{
    u16* As = L;            // 3 x 8192
    u16* Bs = L + 24576;    // 3 x 4096

    const int ntile = ((ntR & 7) << 3) | (ntR >> 3);  // XCD swizzle
    const int nBase = ntile * 64;
    const int mBase = mtile * 128;
    const int tid   = threadIdx.x;
    const int lane  = tid & 63;
    const int wv    = tid >> 6;
    const int quad  = lane >> 4;
    const int l16   = lane & 15;

    const int kStart = kz * (ITERS * 64);

    const int rl   = lane >> 3;
    const int gsl  = lane & 7;
    const int gsrc = gsl ^ rl;

    f32x4 acc[2][4];
#pragma unroll
    for (int i = 0; i < 2; ++i)
#pragma unroll
        for (int j = 0; j < 4; ++j) acc[i][j] = (f32x4){0.f, 0.f, 0.f, 0.f};

    auto stage = [&](int buf, int k0) {
#pragma unroll
        for (int j = 0; j < 4; ++j) {
            const int rb = (wv * 4 + j) * 8;   // 0..120
            gload_lds16(Z + (size_t)(mBase + rb + rl) * NN + k0 + gsrc * 8,
                        &As[buf * 8192 + rb * 64]);
        }
#pragma unroll
        for (int j = 0; j < 2; ++j) {
            const int rb = (wv * 2 + j) * 8;   // 0..56
            gload_lds16(S + (size_t)(nBase + rb + rl) * NN + k0 + gsrc * 8,
                        &Bs[buf * 4096 + rb * 64]);
        }
    };

    auto compute = [&](int buf) {
#pragma unroll
        for (int s = 0; s < 2; ++s) {
            const int g = s * 4 + quad;        // k-granule 0..7
            bf16x8 af[2], bf[4];
#pragma unroll
            for (int mi = 0; mi < 2; ++mi) {
                const int r = wv * 32 + mi * 16 + l16;
                af[mi] = *(const bf16x8*)&As[buf * 8192 + r * 64 + ((g ^ (r & 7)) << 3)];
            }
#pragma unroll
            for (int ni = 0; ni < 4; ++ni) {
                const int r = ni * 16 + l16;
                bf[ni] = *(const bf16x8*)&Bs[buf * 4096 + r * 64 + ((g ^ (r & 7)) << 3)];
            }
#pragma unroll
            for (int mi = 0; mi < 2; ++mi)
#pragma unroll
                for (int ni = 0; ni < 4; ++ni)
                    acc[mi][ni] = __builtin_amdgcn_mfma_f32_16x16x32_bf16(
                        af[mi], bf[ni], acc[mi][ni], 0, 0, 0);
        }
    };

    stage(0, kStart);
    stage(1, kStart + 64);

#pragma unroll
    for (int i = 0; i < ITERS; ++i) {
        if (i + 2 < ITERS) stage((i + 2) % 3, kStart + (i + 2) * 64);
        if (i < ITERS - 2)
            asm volatile("s_waitcnt vmcnt(12)" ::: "memory");
        else if (i == ITERS - 2)
            asm volatile("s_waitcnt vmcnt(6)" ::: "memory");
        else
            asm volatile("s_waitcnt vmcnt(0)" ::: "memory");
        __builtin_amdgcn_s_barrier();
        compute(i % 3);
        if (i + 1 < ITERS) __builtin_amdgcn_s_barrier();
    }

    asm volatile("s_waitcnt lgkmcnt(0)" ::: "memory");
    __builtin_amdgcn_s_barrier();

    // Per-wave transpose: 32 rows x 72 u16; D: col=lane&15, row=quad*4+i.
    u16* tb = &As[wv * 2304];
#pragma unroll
    for (int mi = 0; mi < 2; ++mi)
#pragma unroll
        for (int ni = 0; ni < 4; ++ni)
#pragma unroll
            for (int i = 0; i < 4; ++i)
                tb[(mi * 16 + quad * 4 + i) * 72 + ni * 16 + l16] =
                    f2bf(acc[mi][ni][i]);

    const size_t plane = (size_t)MT * 128 * NN;
    u16* pp = Part + (size_t)kz * plane;
    const int row0g = mBase + wv * 32;
#pragma unroll
    for (int j = 0; j < 4; ++j) {
        const int r = (lane >> 3) + j * 8;      // 0..31
        const int c = (lane & 7) * 8;           // 0..56
        bf16x8 v = *(const bf16x8*)&tb[r * 72 + c];
        *(bf16x8*)&pp[(size_t)(row0g + r) * NN + nBase + c] = v;
    }
}

// ---------------------------------------------------------------------------
// Phase: diffusion with FUSED f32 S conversion (R12 cvtB; M=128, mBase=0).
// LDS: As = L[0..16384) (2 x 8192), Bs = L[16384..24576) (2 x 4096).
// ---------------------------------------------------------------------------
template <int ITERS>
__device__ void dev_cvtB(u16* L, const u16* __restrict__ Z,
                         const float* __restrict__ Sf, u16* __restrict__ Part,
                         u16* __restrict__ Sb, int ntR, int kz)
{
    u16* As = L;            // 2 x 8192
    u16* Bs = L + 16384;    // 2 x 4096

    const int ntile = ((ntR & 7) << 3) | (ntR >> 3);
    const int nBase = ntile * 64;
    const int tid   = threadIdx.x;
    const int lane  = tid & 63;
    const int wv    = tid >> 6;
    const int quad  = lane >> 4;
    const int l16   = lane & 15;

    const int kStart = kz * (ITERS * 64);

    const int rl   = lane >> 3;
    const int gsl  = lane & 7;
    const int gsrc = gsl ^ rl;

    f32x4 acc[2][4];
#pragma unroll
    for (int i = 0; i < 2; ++i)
#pragma unroll
        for (int j = 0; j < 4; ++j) acc[i][j] = (f32x4){0.f, 0.f, 0.f, 0.f};

    auto stageA = [&](int buf, int k0) {
#pragma unroll
        for (int j = 0; j < 4; ++j) {
            const int rb = (wv * 4 + j) * 8;
            gload_lds16(Z + (size_t)(rb + rl) * NN + k0 + gsrc * 8,
                        &As[buf * 8192 + rb * 64]);
        }
    };

    float4 fB[2][2];
    auto loadB = [&](int k0) {
#pragma unroll
        for (int j = 0; j < 2; ++j) {
            const int row = nBase + (wv * 2 + j) * 8 + rl;
            const float* p = Sf + (size_t)row * NN + k0 + gsrc * 8;
            fB[j][0] = *(const float4*)p;
            fB[j][1] = *(const float4*)(p + 4);
        }
    };
    auto writeB = [&](int buf, int k0) {
#pragma unroll
        for (int j = 0; j < 2; ++j) {
            const int rloc = (wv * 2 + j) * 8 + rl;       // 0..63
            bf16x8 v;
            v[0] = (short)f2bf(fB[j][0].x); v[1] = (short)f2bf(fB[j][0].y);
            v[2] = (short)f2bf(fB[j][0].z); v[3] = (short)f2bf(fB[j][0].w);
            v[4] = (short)f2bf(fB[j][1].x); v[5] = (short)f2bf(fB[j][1].y);
            v[6] = (short)f2bf(fB[j][1].z); v[7] = (short)f2bf(fB[j][1].w);
            *(bf16x8*)&Bs[buf * 4096 + rloc * 64 + gsl * 8] = v;
            *(bf16x8*)&Sb[(size_t)(nBase + rloc) * NN + k0 + gsrc * 8] = v;
        }
    };

    auto compute = [&](int buf) {
#pragma unroll
        for (int s = 0; s < 2; ++s) {
            const int g = s * 4 + quad;
            bf16x8 af[2], bf[4];
#pragma unroll
            for (int mi = 0; mi < 2; ++mi) {
                const int r = wv * 32 + mi * 16 + l16;
                af[mi] = *(const bf16x8*)&As[buf * 8192 + r * 64 + ((g ^ (r & 7)) << 3)];
            }
#pragma unroll
            for (int ni = 0; ni < 4; ++ni) {
                const int r = ni * 16 + l16;
                bf[ni] = *(const bf16x8*)&Bs[buf * 4096 + r * 64 + ((g ^ (r & 7)) << 3)];
            }
#pragma unroll
            for (int mi = 0; mi < 2; ++mi)
#pragma unroll
                for (int ni = 0; ni < 4; ++ni)
                    acc[mi][ni] = __builtin_amdgcn_mfma_f32_16x16x32_bf16(
                        af[mi], bf[ni], acc[mi][ni], 0, 0, 0);
        }
    };

    loadB(kStart);
    stageA(0, kStart);
    writeB(0, kStart);
    __syncthreads();

#pragma unroll
    for (int i = 0; i < ITERS; ++i) {
        const int cur = i & 1;
        if (i + 1 < ITERS) {
            stageA(cur ^ 1, kStart + (i + 1) * 64);
            loadB(kStart + (i + 1) * 64);
        }
        compute(cur);
        if (i + 1 < ITERS) writeB(cur ^ 1, kStart + (i + 1) * 64);
        __syncthreads();
    }

    u16* tb = &As[wv * 2304];
#pragma unroll
    for (int mi = 0; mi < 2; ++mi)
#pragma unroll
        for (int ni = 0; ni < 4; ++ni)
#pragma unroll
            for (int i = 0; i < 4; ++i)
                tb[(mi * 16 + quad * 4 + i) * 72 + ni * 16 + l16] =
                    f2bf(acc[mi][ni][i]);

    const size_t plane = (size_t)128 * NN;
    u16* pp = Part + (size_t)kz * plane;
    const int row0g = wv * 32;
#pragma unroll
    for (int j = 0; j < 4; ++j) {
        const int r = (lane >> 3) + j * 8;
        const int c = (lane & 7) * 8;
        bf16x8 v = *(const bf16x8*)&tb[r * 72 + c];
        *(bf16x8*)&pp[(size_t)(row0g + r) * NN + nBase + c] = v;
    }
}

// ---------------------------------------------------------------------------
// Phase: sum KS bf16 partial planes -> bf16 z (grid-stride over NB blocks).
// ---------------------------------------------------------------------------
template <int KS>
__device__ void dev_reduce(const u16* __restrict__ part, int planeElems,
                           u16* __restrict__ outb)
{
    const int base   = (blockIdx.x * 256 + threadIdx.x) * 8;
    const int stride = NB * 256 * 8;
    for (int i = base; i < planeElems; i += stride) {
        float s[8];
#pragma unroll
        for (int e = 0; e < 8; ++e) s[e] = 0.f;
#pragma unroll
        for (int p = 0; p < KS; ++p) {
            uint4 v = *(const uint4*)(part + (size_t)p * planeElems + i);
            const u32 w[4] = {v.x, v.y, v.z, v.w};
#pragma unroll
            for (int q = 0; q < 4; ++q) {
                union { u32 i; float f; } lo, hi;
                lo.i = w[q] << 16;
                hi.i = w[q] & 0xFFFF0000u;
                s[q * 2]     += lo.f;
                s[q * 2 + 1] += hi.f;
            }
        }
        uint4 o;
        o.x = (u32)f2bf(s[0]) | ((u32)f2bf(s[1]) << 16);
        o.y = (u32)f2bf(s[2]) | ((u32)f2bf(s[3]) << 16);
        o.z = (u32)f2bf(s[4]) | ((u32)f2bf(s[5]) << 16);
        o.w = (u32)f2bf(s[6]) | ((u32)f2bf(s[7]) << 16);
        *(uint4*)(outb + i) = o;
    }
}

// ---------------------------------------------------------------------------
// Phase: tap combine + ReLU (blocks 0..127 do work; all blocks return).
// ---------------------------------------------------------------------------
template <int FIN, int FOUT, int KS>
__device__ void dev_combine(u16* L, const u16* __restrict__ z0,
                            const u16* __restrict__ z1,
                            const u16* __restrict__ part2, int planeElems,
                            const float* __restrict__ W,
                            const float* __restrict__ bias,
                            u16* __restrict__ out)
{
    float* hs = (float*)L;
    float* bs = hs + FOUT * 3 * FIN;
    for (int i = threadIdx.x; i < FOUT * 3 * FIN; i += 256) hs[i] = W[i];
    if (threadIdx.x < FOUT) bs[threadIdx.x] = bias[threadIdx.x];
    __syncthreads();

    const int b = blockIdx.x >> 4;                      // nb = 16
    const int n = (blockIdx.x & 15) * 256 + threadIdx.x;

    float zv[3][FIN];
    const u16* zp0 = z0 + (size_t)b * FIN * NN + n;
    const u16* zp1 = z1 + (size_t)b * FIN * NN + n;
    const u16* zp2 = part2 + (size_t)b * FIN * NN + n;
#pragma unroll
    for (int f = 0; f < FIN; ++f) {
        zv[0][f] = bf2f(zp0[(size_t)f * NN]);
        zv[1][f] = bf2f(zp1[(size_t)f * NN]);
        float s = 0.f;
#pragma unroll
        for (int p = 0; p < KS; ++p)
            s += bf2f(zp2[(size_t)p * planeElems + (size_t)f * NN]);
        zv[2][f] = s;
    }

    u16* op = out + (size_t)b * FOUT * NN + n;
    for (int g = 0; g < FOUT; ++g) {
        float acc = bs[g];
#pragma unroll
        for (int k = 0; k < 3; ++k)
#pragma unroll
            for (int f = 0; f < FIN; ++f)
                acc = fmaf(hs[(g * 3 + k) * FIN + f], zv[k][f], acc);
        op[(size_t)g * NN] = f2bf(fmaxf(acc, 0.f));
    }
}

// ---------------------------------------------------------------------------
// Phase: MLP layer 1 split-K (NB blocks: j = bx&63, slice = bx>>6).
// ---------------------------------------------------------------------------
__device__ void dev_mlp1(u16* L, const u16* __restrict__ y,
                         const float* __restrict__ Wm1, float* __restrict__ h1p)
{
    const int j     = blockIdx.x & 63;
    const int slice = blockIdx.x >> 6;
    const int base  = slice * 8192;
    const int D     = 16 * NN;  // 65536

    float acc[BB];
#pragma unroll
    for (int b = 0; b < BB; ++b) acc[b] = 0.f;

    const float* wrow = Wm1 + (size_t)j * D + base;
    for (int idx = threadIdx.x * 8; idx < 8192; idx += 256 * 8) {
        float4 w0 = *(const float4*)(wrow + idx);
        float4 w1 = *(const float4*)(wrow + idx + 4);
#pragma unroll
        for (int b = 0; b < BB; ++b) {
            uint4 yv = *(const uint4*)(y + (size_t)b * D + base + idx);
            union { u32 i; float f; } c[8];
            c[0].i = yv.x << 16; c[1].i = yv.x & 0xFFFF0000u;
            c[2].i = yv.y << 16; c[3].i = yv.y & 0xFFFF0000u;
            c[4].i = yv.z << 16; c[5].i = yv.z & 0xFFFF0000u;
            c[6].i = yv.w << 16; c[7].i = yv.w & 0xFFFF0000u;
            acc[b] = fmaf(w0.x, c[0].f, acc[b]);
            acc[b] = fmaf(w0.y, c[1].f, acc[b]);
            acc[b] = fmaf(w0.z, c[2].f, acc[b]);
            acc[b] = fmaf(w0.w, c[3].f, acc[b]);
            acc[b] = fmaf(w1.x, c[4].f, acc[b]);
            acc[b] = fmaf(w1.y, c[5].f, acc[b]);
            acc[b] = fmaf(w1.z, c[6].f, acc[b]);
            acc[b] = fmaf(w1.w, c[7].f, acc[b]);
        }
    }

    float* red = (float*)L;   // [BB][4]
    const int lane = threadIdx.x & 63;
    const int w    = threadIdx.x >> 6;
#pragma unroll
    for (int b = 0; b < BB; ++b) {
        float v = acc[b];
        for (int off = 32; off > 0; off >>= 1) v += __shfl_down(v, off, 64);
        if (lane == 0) red[b * 4 + w] = v;
    }
    __syncthreads();
    if (threadIdx.x < BB) {
        const int b = threadIdx.x;
        h1p[slice * (BB * 64) + b * 64 + j] =
            red[b * 4 + 0] + red[b * 4 + 1] + red[b * 4 + 2] + red[b * 4 + 3];
    }
}

// ---------------------------------------------------------------------------
// Phase: MLP layer 2 (+ slice-sum + bias/ReLU). Block 0, lanes 0..63.
// ---------------------------------------------------------------------------
__device__ void dev_mlp2(const float* __restrict__ h1p,
                         const float* __restrict__ bm1,
                         const float* __restrict__ Wm2,
                         const float* __restrict__ bm2, float* __restrict__ out)
{
    if (threadIdx.x >= 64) return;
    const int lane = threadIdx.x;
    const float w    = Wm2[lane];
    const float b1   = bm1[lane];
    const float bias = bm2[0];
    for (int b = 0; b < BB; ++b) {
        float h = 0.f;
#pragma unroll
        for (int p = 0; p < 8; ++p) h += h1p[p * (BB * 64) + b * 64 + lane];
        float v = fmaxf(h + b1, 0.f) * w;
        for (int off = 32; off > 0; off >>= 1) v += __shfl_down(v, off, 64);
        if (lane == 0) out[b] = v + bias;
    }
}

// ---------------------------------------------------------------------------
// One GNN layer as a persistent kernel. NB=512 blocks x 256 threads, 72 KB
// LDS, __launch_bounds__(256,2) -> 2 blocks/CU x 256 CU, all co-resident.
// Phases: [DO_X: x f32->bf16] -> diffuse1 (CVTB: fused S-convert) -> reduce
// -> diffuse2 -> combine -> [DO_MLP: mlp1 -> mlp2], separated by gridbar.
// ---------------------------------------------------------------------------
template <int FIN, int FOUT, int KS, int ITERS, int MT,
          bool CVTB, bool DO_X, bool DO_MLP>
__global__ __launch_bounds__(256, 2) void layer_k(
    const float* xf, u16* zio, const float* Sf, u16* Sb,
    u16* part, u16* zb1, u16* zout,
    const float* W, const float* bias,
    const float* Wm1, float* h1p, const float* bm1,
    const float* Wm2, const float* bm2, float* outp, u32* ctr)
{
    __shared__ __align__(16) u16 L[36864];   // 72 KB
    const int bx   = blockIdx.x;
    const int ntR  = bx & 63;
    const int rest = bx >> 6;
    const int mtile = rest & (MT - 1);
    const int kz    = rest / MT;
    const int planeElems = MT * 128 * NN;
    u32 tgt = 0;

    if constexpr (DO_X) {
        // NB blocks x 256 thr x 4 floats = 524288 = |x| exactly.
        const int i = (bx * 256 + threadIdx.x) * 4;
        float4 v = *(const float4*)(xf + i);
        ushort4 o;
        o.x = f2bf(v.x); o.y = f2bf(v.y); o.z = f2bf(v.z); o.w = f2bf(v.w);
        *(ushort4*)(zio + i) = o;
        gridbar(ctr, tgt += NB);
    }

    if constexpr (CVTB)
        dev_cvtB<ITERS>(L, zio, Sf, part, Sb, ntR, kz);
    else
        dev_diffuse<ITERS, MT>(L, zio, Sb, part, ntR, mtile, kz);
    gridbar(ctr, tgt += NB);

    dev_reduce<KS>(part, planeElems, zb1);
    gridbar(ctr, tgt += NB);

    dev_diffuse<ITERS, MT>(L, zb1, Sb, part, ntR, mtile, kz);
    gridbar(ctr, tgt += NB);

    if (bx < 128)
        dev_combine<FIN, FOUT, KS>(L, zio, zb1, part, planeElems, W, bias, zout);

    if constexpr (DO_MLP) {
        gridbar(ctr, tgt += NB);
        dev_mlp1(L, zout, Wm1, h1p);
        gridbar(ctr, tgt += NB);
        if (bx == 0) dev_mlp2(h1p, bm1, Wm2, bm2, outp);
    }
}

// ---------------------------------------------------------------------------
extern "C" void kernel_launch(void* const* d_in, const int* in_sizes, int n_in,
                              void* d_out, int out_size, void* d_ws, size_t ws_size,
                              hipStream_t stream)
{
    const float* x   = (const float*)d_in[0];   // [8,16,4096]
    const float* Sc  = (const float*)d_in[1];   // [1,4096,4096]
    const float* Sl  = (const float*)d_in[2];   // [1,4096,4096]
    const float* Wc1 = (const float*)d_in[3];
    const float* bc1 = (const float*)d_in[4];
    const float* Wc2 = (const float*)d_in[5];
    const float* bc2 = (const float*)d_in[6];
    const float* Wl1 = (const float*)d_in[7];
    const float* bl1 = (const float*)d_in[8];
    const float* Wl2 = (const float*)d_in[9];
    const float* bl2 = (const float*)d_in[10];
    const float* Wm1 = (const float*)d_in[11];  // [64,65536]
    const float* bm1 = (const float*)d_in[12];
    const float* Wm2 = (const float*)d_in[13];  // [1,64]
    const float* bm2 = (const float*)d_in[14];
    float* out = (float*)d_out;                 // [8,1] f32

    char* ws = (char*)d_ws;                      // proven >= 81.02 MB
    u16*   part = (u16*)(ws);                    // 8 MB partial planes
    u16*   zb1  = (u16*)(ws + (8u  << 20));      // 2 MB
    u16*   yPa  = (u16*)(ws + (12u << 20));      // 2 MB
    u16*   yPb  = (u16*)(ws + (14u << 20));      // 2 MB
    float* h1p  = (float*)(ws + (16u << 20));    // 16 KB
    u32*   ctr  = (u32*)(ws + (16u << 20) + 32768);  // 4 x u32 barrier ctrs
    u16*   Scb  = (u16*)(ws + (17u << 20));      // 32 MB
    u16*   Slb  = Scb + (size_t)NN * NN;         // 32 MB  (total 81.02 MB)

    dim3 g(NB), b(256);

    hipMemsetAsync(ctr, 0, 4 * sizeof(u32), stream);

    // Layer 1: clique, Fin=16 -> 32.  x-cvt + Sc f32 read (writes Scb).
    layer_k<16, 32, 8, 8, 1, true, true, false><<<g, b, 0, stream>>>(
        x, yPa, Sc, Scb, part, zb1, yPb, Wc1, bc1,
        Wm1, h1p, bm1, Wm2, bm2, out, ctr + 0);
    // Layer 2: clique, Fin=32 -> 16 (M=256).
    layer_k<32, 16, 4, 16, 2, false, false, false><<<g, b, 0, stream>>>(
        x, yPb, Sc, Scb, part, zb1, yPa, Wc2, bc2,
        Wm1, h1p, bm1, Wm2, bm2, out, ctr + 1);
    // Layer 3: line, Fin=16 -> 32.  Sl f32 read (writes Slb).
    layer_k<16, 32, 8, 8, 1, true, false, false><<<g, b, 0, stream>>>(
        x, yPa, Sl, Slb, part, zb1, yPb, Wl1, bl1,
        Wm1, h1p, bm1, Wm2, bm2, out, ctr + 2);
    // Layer 4: line, Fin=32 -> 16 (M=256) + MLP head.
    layer_k<32, 16, 4, 16, 2, false, false, true><<<g, b, 0, stream>>>(
        x, yPb, Sl, Slb, part, zb1, yPa, Wl2, bl2,
        Wm1, h1p, bm1, Wm2, bm2, out, ctr + 3);
}

// Round 11
// 1244.717 us; speedup vs baseline: 1.6008x; 1.6008x over previous
//
#include <hip/hip_runtime.h>

// SelectionGNN clique+line. I/O: float32. Internals: bf16 end-to-end with f32
// accumulation (MFMA + reduce). B=8, N=4096, E=1, K=3, F=[16,32,16],
// MLP 65536->64->1.
// R17: R16's persistent fusion with the gridbar pathology fixed. R16 was
//     CORRECT but 5.4x slow; counters showed phases uniformly stretched
//     (HBM 2.4%, Mfma 1.1%) -> the barrier itself throttled the chip:
//     (a) every-thread __threadfence = 262k fence execs (2048 wave-level
//         buffer_wbl2 L2-writeback commands) per barrier;
//     (b) s_sleep(8) poll = ~880 same-line agent loads/us (saturates the
//         coherence point, queues real traffic behind it).
//     Fix: per-wave s_waitcnt drain + ONE release fence and ONE acquire
//     fence per block (thread 0; wbl2/inv are cache-wide so one instruction
//     covers the block), and s_sleep(64) (~1.7us/poll, ~245 polls/us).
//     All else identical to R16 (phases = R12's verified kernels).

#define NN 4096
#define BB 8
#define NB 512   // blocks per fused kernel

typedef unsigned short u16;
typedef unsigned int   u32;

typedef __attribute__((ext_vector_type(8))) short bf16x8;  // 8 bf16 = 4 VGPRs
typedef __attribute__((ext_vector_type(4))) float f32x4;

__device__ __forceinline__ u16 f2bf(float f) {
    union { float f; u32 i; } c; c.f = f;
    u32 i = c.i;
    u32 r = (i + 0x7FFFu + ((i >> 16) & 1u)) >> 16;  // RTNE
    return (u16)r;
}
__device__ __forceinline__ float bf2f(u16 u) {
    union { u32 i; float f; } c; c.i = ((u32)u) << 16; return c.f;
}

__device__ __forceinline__ void gload_lds16(const u16* g, u16* l) {
    __builtin_amdgcn_global_load_lds(
        (__attribute__((address_space(1))) void*)g,
        (__attribute__((address_space(3))) void*)l, 16, 0, 0);
}

// ---------------------------------------------------------------------------
// Device-scope grid barrier, low-contention form. All NB blocks co-resident
// by construction (proven by R16's correct completion).
// Per wave: s_waitcnt drains its own stores to L2. Then ONE thread per block
// does release fence (buffer_wbl2, cache-wide for its XCD) -> relaxed
// atomicAdd arrival -> throttled poll (s_sleep(64) ~ 1.7us) -> acquire fence
// (buffer_inv, covers the CU L1 + XCD L2 stale lines). __syncthreads
// publishes to the other waves. Targets monotonic; one counter per kernel.
// ---------------------------------------------------------------------------
__device__ __forceinline__ void gridbar(u32* ctr, u32 target) {
    asm volatile("s_waitcnt vmcnt(0) lgkmcnt(0)" ::: "memory");
    __syncthreads();
    if (threadIdx.x == 0) {
        __threadfence();   // release: one wbl2 for the whole block's writes
        __hip_atomic_fetch_add(ctr, 1u, __ATOMIC_RELAXED,
                               __HIP_MEMORY_SCOPE_AGENT);
        while (__hip_atomic_load(ctr, __ATOMIC_RELAXED,
                                 __HIP_MEMORY_SCOPE_AGENT) < target)
            __builtin_amdgcn_s_sleep(64);
        __threadfence();   // acquire: one inv for the block's readers
    }
    __syncthreads();
}

// ---------------------------------------------------------------------------
// Phase: split-K diffusion (R12 structure). 128(M) x 64(N) tile, BK=64.
// LDS: As = L[0..24576) (3 x 8192 u16), Bs = L[24576..36864) (3 x 4096 u16).
// 3-buffer depth-2 pipeline, counted vmcnt(12/6/0) + raw s_barrier.
// ---------------------------------------------------------------------------
template <int ITERS, int MT>
__device__ void dev_diffuse(u16* L, const u16* __restrict__ Z,
                            const u16* __restrict__ S, u16* __restrict__ Part,
                            int ntR, int mtile, int kz)
{
    u16* As = L;            // 3 x 8192
    u16* Bs = L + 24576;    // 3 x 4096

    const int ntile = ((ntR & 7) << 3) | (ntR >> 3);  // XCD swizzle
    const int nBase = ntile * 64;
    const int mBase = mtile * 128;
    const int tid   = threadIdx.x;
    const int lane  = tid & 63;
    const int wv    = tid >> 6;
    const int quad  = lane >> 4;
    const int l16   = lane & 15;

    const int kStart = kz * (ITERS * 64);

    const int rl   = lane >> 3;
    const int gsl  = lane & 7;
    const int gsrc = gsl ^ rl;

    f32x4 acc[2][4];
#pragma unroll
    for (int i = 0; i < 2; ++i)
#pragma unroll
        for (int j = 0; j < 4; ++j) acc[i][j] = (f32x4){0.f, 0.f, 0.f, 0.f};

    auto stage = [&](int buf, int k0) {
#pragma unroll
        for (int j = 0; j < 4; ++j) {
            const int rb = (wv * 4 + j) * 8;   // 0..120
            gload_lds16(Z + (size_t)(mBase + rb + rl) * NN + k0 + gsrc * 8,
                        &As[buf * 8192 + rb * 64]);
        }
#pragma unroll
        for (int j = 0; j < 2; ++j) {
            const int rb = (wv * 2 + j) * 8;   // 0..56
            gload_lds16(S + (size_t)(nBase + rb + rl) * NN + k0 + gsrc * 8,
                        &Bs[buf * 4096 + rb * 64]);
        }
    };

    auto compute = [&](int buf) {
#pragma unroll
        for (int s = 0; s < 2; ++s) {
            const int g = s * 4 + quad;        // k-granule 0..7
            bf16x8 af[2], bf[4];
#pragma unroll
            for (int mi = 0; mi < 2; ++mi) {
                const int r = wv * 32 + mi * 16 + l16;
                af[mi] = *(const bf16x8*)&As[buf * 8192 + r * 64 + ((g ^ (r & 7)) << 3)];
            }
#pragma unroll
            for (int ni = 0; ni < 4; ++ni) {
                const int r = ni * 16 + l16;
                bf[ni] = *(const bf16x8*)&Bs[buf * 4096 + r * 64 + ((g ^ (r & 7)) << 3)];
            }
#pragma unroll
            for (int mi = 0; mi < 2; ++mi)
#pragma unroll
                for (int ni = 0; ni < 4; ++ni)
                    acc[mi][ni] = __builtin_amdgcn_mfma_f32_16x16x32_bf16(
                        af[mi], bf[ni], acc[mi][ni], 0, 0, 0);
        }
    };

    stage(0, kStart);
    stage(1, kStart + 64);

#pragma unroll
    for (int i = 0; i < ITERS; ++i) {
        if (i + 2 < ITERS) stage((i + 2) % 3, kStart + (i + 2) * 64);
        if (i < ITERS - 2)
            asm volatile("s_waitcnt vmcnt(12)" ::: "memory");
        else if (i == ITERS - 2)
            asm volatile("s_waitcnt vmcnt(6)" ::: "memory");
        else
            asm volatile("s_waitcnt vmcnt(0)" ::: "memory");
        __builtin_amdgcn_s_barrier();
        compute(i % 3);
        if (i + 1 < ITERS) __builtin_amdgcn_s_barrier();
    }

    asm volatile("s_waitcnt lgkmcnt(0)" ::: "memory");
    __builtin_amdgcn_s_barrier();

    // Per-wave transpose: 32 rows x 72 u16; D: col=lane&15, row=quad*4+i.
    u16* tb = &As[wv * 2304];
#pragma unroll
    for (int mi = 0; mi < 2; ++mi)
#pragma unroll
        for (int ni = 0; ni < 4; ++ni)
#pragma unroll
            for (int i = 0; i < 4; ++i)
                tb[(mi * 16 + quad * 4 + i) * 72 + ni * 16 + l16] =
                    f2bf(acc[mi][ni][i]);

    const size_t plane = (size_t)MT * 128 * NN;
    u16* pp = Part + (size_t)kz * plane;
    const int row0g = mBase + wv * 32;
#pragma unroll
    for (int j = 0; j < 4; ++j) {
        const int r = (lane >> 3) + j * 8;      // 0..31
        const int c = (lane & 7) * 8;           // 0..56
        bf16x8 v = *(const bf16x8*)&tb[r * 72 + c];
        *(bf16x8*)&pp[(size_t)(row0g + r) * NN + nBase + c] = v;
    }
}

// ---------------------------------------------------------------------------
// Phase: diffusion with FUSED f32 S conversion (R12 cvtB; M=128, mBase=0).
// LDS: As = L[0..16384) (2 x 8192), Bs = L[16384..24576) (2 x 4096).
// ---------------------------------------------------------------------------
template <int ITERS>
__device__ void dev_cvtB(u16* L, const u16* __restrict__ Z,
                         const float* __restrict__ Sf, u16* __restrict__ Part,
                         u16* __restrict__ Sb, int ntR, int kz)
{
    u16* As = L;            // 2 x 8192
    u16* Bs = L + 16384;    // 2 x 4096

    const int ntile = ((ntR & 7) << 3) | (ntR >> 3);
    const int nBase = ntile * 64;
    const int tid   = threadIdx.x;
    const int lane  = tid & 63;
    const int wv    = tid >> 6;
    const int quad  = lane >> 4;
    const int l16   = lane & 15;

    const int kStart = kz * (ITERS * 64);

    const int rl   = lane >> 3;
    const int gsl  = lane & 7;
    const int gsrc = gsl ^ rl;

    f32x4 acc[2][4];
#pragma unroll
    for (int i = 0; i < 2; ++i)
#pragma unroll
        for (int j = 0; j < 4; ++j) acc[i][j] = (f32x4){0.f, 0.f, 0.f, 0.f};

    auto stageA = [&](int buf, int k0) {
#pragma unroll
        for (int j = 0; j < 4; ++j) {
            const int rb = (wv * 4 + j) * 8;
            gload_lds16(Z + (size_t)(rb + rl) * NN + k0 + gsrc * 8,
                        &As[buf * 8192 + rb * 64]);
        }
    };

    float4 fB[2][2];
    auto loadB = [&](int k0) {
#pragma unroll
        for (int j = 0; j < 2; ++j) {
            const int row = nBase + (wv * 2 + j) * 8 + rl;
            const float* p = Sf + (size_t)row * NN + k0 + gsrc * 8;
            fB[j][0] = *(const float4*)p;
            fB[j][1] = *(const float4*)(p + 4);
        }
    };
    auto writeB = [&](int buf, int k0) {
#pragma unroll
        for (int j = 0; j < 2; ++j) {
            const int rloc = (wv * 2 + j) * 8 + rl;       // 0..63
            bf16x8 v;
            v[0] = (short)f2bf(fB[j][0].x); v[1] = (short)f2bf(fB[j][0].y);
            v[2] = (short)f2bf(fB[j][0].z); v[3] = (short)f2bf(fB[j][0].w);
            v[4] = (short)f2bf(fB[j][1].x); v[5] = (short)f2bf(fB[j][1].y);
            v[6] = (short)f2bf(fB[j][1].z); v[7] = (short)f2bf(fB[j][1].w);
            *(bf16x8*)&Bs[buf * 4096 + rloc * 64 + gsl * 8] = v;
            *(bf16x8*)&Sb[(size_t)(nBase + rloc) * NN + k0 + gsrc * 8] = v;
        }
    };

    auto compute = [&](int buf) {
#pragma unroll
        for (int s = 0; s < 2; ++s) {
            const int g = s * 4 + quad;
            bf16x8 af[2], bf[4];
#pragma unroll
            for (int mi = 0; mi < 2; ++mi) {
                const int r = wv * 32 + mi * 16 + l16;
                af[mi] = *(const bf16x8*)&As[buf * 8192 + r * 64 + ((g ^ (r & 7)) << 3)];
            }
#pragma unroll
            for (int ni = 0; ni < 4; ++ni) {
                const int r = ni * 16 + l16;
                bf[ni] = *(const bf16x8*)&Bs[buf * 4096 + r * 64 + ((g ^ (r & 7)) << 3)];
            }
#pragma unroll
            for (int mi = 0; mi < 2; ++mi)
#pragma unroll
                for (int ni = 0; ni < 4; ++ni)
                    acc[mi][ni] = __builtin_amdgcn_mfma_f32_16x16x32_bf16(
                        af[mi], bf[ni], acc[mi][ni], 0, 0, 0);
        }
    };

    loadB(kStart);
    stageA(0, kStart);
    writeB(0, kStart);
    __syncthreads();

#pragma unroll
    for (int i = 0; i < ITERS; ++i) {
        const int cur = i & 1;
        if (i + 1 < ITERS) {
            stageA(cur ^ 1, kStart + (i + 1) * 64);
            loadB(kStart + (i + 1) * 64);
        }
        compute(cur);
        if (i + 1 < ITERS) writeB(cur ^ 1, kStart + (i + 1) * 64);
        __syncthreads();
    }

    u16* tb = &As[wv * 2304];
#pragma unroll
    for (int mi = 0; mi < 2; ++mi)
#pragma unroll
        for (int ni = 0; ni < 4; ++ni)
#pragma unroll
            for (int i = 0; i < 4; ++i)
                tb[(mi * 16 + quad * 4 + i) * 72 + ni * 16 + l16] =
                    f2bf(acc[mi][ni][i]);

    const size_t plane = (size_t)128 * NN;
    u16* pp = Part + (size_t)kz * plane;
    const int row0g = wv * 32;
#pragma unroll
    for (int j = 0; j < 4; ++j) {
        const int r = (lane >> 3) + j * 8;
        const int c = (lane & 7) * 8;
        bf16x8 v = *(const bf16x8*)&tb[r * 72 + c];
        *(bf16x8*)&pp[(size_t)(row0g + r) * NN + nBase + c] = v;
    }
}

// ---------------------------------------------------------------------------
// Phase: sum KS bf16 partial planes -> bf16 z (grid-stride over NB blocks).
// ---------------------------------------------------------------------------
template <int KS>
__device__ void dev_reduce(const u16* __restrict__ part, int planeElems,
                           u16* __restrict__ outb)
{
    const int base   = (blockIdx.x * 256 + threadIdx.x) * 8;
    const int stride = NB * 256 * 8;
    for (int i = base; i < planeElems; i += stride) {
        float s[8];
#pragma unroll
        for (int e = 0; e < 8; ++e) s[e] = 0.f;
#pragma unroll
        for (int p = 0; p < KS; ++p) {
            uint4 v = *(const uint4*)(part + (size_t)p * planeElems + i);
            const u32 w[4] = {v.x, v.y, v.z, v.w};
#pragma unroll
            for (int q = 0; q < 4; ++q) {
                union { u32 i; float f; } lo, hi;
                lo.i = w[q] << 16;
                hi.i = w[q] & 0xFFFF0000u;
                s[q * 2]     += lo.f;
                s[q * 2 + 1] += hi.f;
            }
        }
        uint4 o;
        o.x = (u32)f2bf(s[0]) | ((u32)f2bf(s[1]) << 16);
        o.y = (u32)f2bf(s[2]) | ((u32)f2bf(s[3]) << 16);
        o.z = (u32)f2bf(s[4]) | ((u32)f2bf(s[5]) << 16);
        o.w = (u32)f2bf(s[6]) | ((u32)f2bf(s[7]) << 16);
        *(uint4*)(outb + i) = o;
    }
}

// ---------------------------------------------------------------------------
// Phase: tap combine + ReLU (blocks 0..127 do work; all blocks return).
// ---------------------------------------------------------------------------
template <int FIN, int FOUT, int KS>
__device__ void dev_combine(u16* L, const u16* __restrict__ z0,
                            const u16* __restrict__ z1,
                            const u16* __restrict__ part2, int planeElems,
                            const float* __restrict__ W,
                            const float* __restrict__ bias,
                            u16* __restrict__ out)
{
    float* hs = (float*)L;
    float* bs = hs + FOUT * 3 * FIN;
    for (int i = threadIdx.x; i < FOUT * 3 * FIN; i += 256) hs[i] = W[i];
    if (threadIdx.x < FOUT) bs[threadIdx.x] = bias[threadIdx.x];
    __syncthreads();

    const int b = blockIdx.x >> 4;                      // nb = 16
    const int n = (blockIdx.x & 15) * 256 + threadIdx.x;

    float zv[3][FIN];
    const u16* zp0 = z0 + (size_t)b * FIN * NN + n;
    const u16* zp1 = z1 + (size_t)b * FIN * NN + n;
    const u16* zp2 = part2 + (size_t)b * FIN * NN + n;
#pragma unroll
    for (int f = 0; f < FIN; ++f) {
        zv[0][f] = bf2f(zp0[(size_t)f * NN]);
        zv[1][f] = bf2f(zp1[(size_t)f * NN]);
        float s = 0.f;
#pragma unroll
        for (int p = 0; p < KS; ++p)
            s += bf2f(zp2[(size_t)p * planeElems + (size_t)f * NN]);
        zv[2][f] = s;
    }

    u16* op = out + (size_t)b * FOUT * NN + n;
    for (int g = 0; g < FOUT; ++g) {
        float acc = bs[g];
#pragma unroll
        for (int k = 0; k < 3; ++k)
#pragma unroll
            for (int f = 0; f < FIN; ++f)
                acc = fmaf(hs[(g * 3 + k) * FIN + f], zv[k][f], acc);
        op[(size_t)g * NN] = f2bf(fmaxf(acc, 0.f));
    }
}

// ---------------------------------------------------------------------------
// Phase: MLP layer 1 split-K (NB blocks: j = bx&63, slice = bx>>6).
// ---------------------------------------------------------------------------
__device__ void dev_mlp1(u16* L, const u16* __restrict__ y,
                         const float* __restrict__ Wm1, float* __restrict__ h1p)
{
    const int j     = blockIdx.x & 63;
    const int slice = blockIdx.x >> 6;
    const int base  = slice * 8192;
    const int D     = 16 * NN;  // 65536

    float acc[BB];
#pragma unroll
    for (int b = 0; b < BB; ++b) acc[b] = 0.f;

    const float* wrow = Wm1 + (size_t)j * D + base;
    for (int idx = threadIdx.x * 8; idx < 8192; idx += 256 * 8) {
        float4 w0 = *(const float4*)(wrow + idx);
        float4 w1 = *(const float4*)(wrow + idx + 4);
#pragma unroll
        for (int b = 0; b < BB; ++b) {
            uint4 yv = *(const uint4*)(y + (size_t)b * D + base + idx);
            union { u32 i; float f; } c[8];
            c[0].i = yv.x << 16; c[1].i = yv.x & 0xFFFF0000u;
            c[2].i = yv.y << 16; c[3].i = yv.y & 0xFFFF0000u;
            c[4].i = yv.z << 16; c[5].i = yv.z & 0xFFFF0000u;
            c[6].i = yv.w << 16; c[7].i = yv.w & 0xFFFF0000u;
            acc[b] = fmaf(w0.x, c[0].f, acc[b]);
            acc[b] = fmaf(w0.y, c[1].f, acc[b]);
            acc[b] = fmaf(w0.z, c[2].f, acc[b]);
            acc[b] = fmaf(w0.w, c[3].f, acc[b]);
            acc[b] = fmaf(w1.x, c[4].f, acc[b]);
            acc[b] = fmaf(w1.y, c[5].f, acc[b]);
            acc[b] = fmaf(w1.z, c[6].f, acc[b]);
            acc[b] = fmaf(w1.w, c[7].f, acc[b]);
        }
    }

    float* red = (float*)L;   // [BB][4]
    const int lane = threadIdx.x & 63;
    const int w    = threadIdx.x >> 6;
#pragma unroll
    for (int b = 0; b < BB; ++b) {
        float v = acc[b];
        for (int off = 32; off > 0; off >>= 1) v += __shfl_down(v, off, 64);
        if (lane == 0) red[b * 4 + w] = v;
    }
    __syncthreads();
    if (threadIdx.x < BB) {
        const int b = threadIdx.x;
        h1p[slice * (BB * 64) + b * 64 + j] =
            red[b * 4 + 0] + red[b * 4 + 1] + red[b * 4 + 2] + red[b * 4 + 3];
    }
}

// ---------------------------------------------------------------------------
// Phase: MLP layer 2 (+ slice-sum + bias/ReLU). Block 0, lanes 0..63.
// ---------------------------------------------------------------------------
__device__ void dev_mlp2(const float* __restrict__ h1p,
                         const float* __restrict__ bm1,
                         const float* __restrict__ Wm2,
                         const float* __restrict__ bm2, float* __restrict__ out)
{
    if (threadIdx.x >= 64) return;
    const int lane = threadIdx.x;
    const float w    = Wm2[lane];
    const float b1   = bm1[lane];
    const float bias = bm2[0];
    for (int b = 0; b < BB; ++b) {
        float h = 0.f;
#pragma unroll
        for (int p = 0; p < 8; ++p) h += h1p[p * (BB * 64) + b * 64 + lane];
        float v = fmaxf(h + b1, 0.f) * w;
        for (int off = 32; off > 0; off >>= 1) v += __shfl_down(v, off, 64);
        if (lane == 0) out[b] = v + bias;
    }
}

// ---------------------------------------------------------------------------
// One GNN layer as a persistent kernel. NB=512 blocks x 256 threads, 72 KB
// LDS, __launch_bounds__(256,2) -> 2 blocks/CU x 256 CU, all co-resident.
// Phases: [DO_X: x f32->bf16] -> diffuse1 (CVTB: fused S-convert) -> reduce
// -> diffuse2 -> combine -> [DO_MLP: mlp1 -> mlp2], separated by gridbar.
// ---------------------------------------------------------------------------
template <int FIN, int FOUT, int KS, int ITERS, int MT,
          bool CVTB, bool DO_X, bool DO_MLP>
__global__ __launch_bounds__(256, 2) void layer_k(
    const float* xf, u16* zio, const float* Sf, u16* Sb,
    u16* part, u16* zb1, u16* zout,
    const float* W, const float* bias,
    const float* Wm1, float* h1p, const float* bm1,
    const float* Wm2, const float* bm2, float* outp, u32* ctr)
{
    __shared__ __align__(16) u16 L[36864];   // 72 KB
    const int bx   = blockIdx.x;
    const int ntR  = bx & 63;
    const int rest = bx >> 6;
    const int mtile = rest & (MT - 1);
    const int kz    = rest / MT;
    const int planeElems = MT * 128 * NN;
    u32 tgt = 0;

    if constexpr (DO_X) {
        // NB blocks x 256 thr x 4 floats = 524288 = |x| exactly.
        const int i = (bx * 256 + threadIdx.x) * 4;
        float4 v = *(const float4*)(xf + i);
        ushort4 o;
        o.x = f2bf(v.x); o.y = f2bf(v.y); o.z = f2bf(v.z); o.w = f2bf(v.w);
        *(ushort4*)(zio + i) = o;
        gridbar(ctr, tgt += NB);
    }

    if constexpr (CVTB)
        dev_cvtB<ITERS>(L, zio, Sf, part, Sb, ntR, kz);
    else
        dev_diffuse<ITERS, MT>(L, zio, Sb, part, ntR, mtile, kz);
    gridbar(ctr, tgt += NB);

    dev_reduce<KS>(part, planeElems, zb1);
    gridbar(ctr, tgt += NB);

    dev_diffuse<ITERS, MT>(L, zb1, Sb, part, ntR, mtile, kz);
    gridbar(ctr, tgt += NB);

    if (bx < 128)
        dev_combine<FIN, FOUT, KS>(L, zio, zb1, part, planeElems, W, bias, zout);

    if constexpr (DO_MLP) {
        gridbar(ctr, tgt += NB);
        dev_mlp1(L, zout, Wm1, h1p);
        gridbar(ctr, tgt += NB);
        if (bx == 0) dev_mlp2(h1p, bm1, Wm2, bm2, outp);
    }
}

// ---------------------------------------------------------------------------
extern "C" void kernel_launch(void* const* d_in, const int* in_sizes, int n_in,
                              void* d_out, int out_size, void* d_ws, size_t ws_size,
                              hipStream_t stream)
{
    const float* x   = (const float*)d_in[0];   // [8,16,4096]
    const float* Sc  = (const float*)d_in[1];   // [1,4096,4096]
    const float* Sl  = (const float*)d_in[2];   // [1,4096,4096]
    const float* Wc1 = (const float*)d_in[3];
    const float* bc1 = (const float*)d_in[4];
    const float* Wc2 = (const float*)d_in[5];
    const float* bc2 = (const float*)d_in[6];
    const float* Wl1 = (const float*)d_in[7];
    const float* bl1 = (const float*)d_in[8];
    const float* Wl2 = (const float*)d_in[9];
    const float* bl2 = (const float*)d_in[10];
    const float* Wm1 = (const float*)d_in[11];  // [64,65536]
    const float* bm1 = (const float*)d_in[12];
    const float* Wm2 = (const float*)d_in[13];  // [1,64]
    const float* bm2 = (const float*)d_in[14];
    float* out = (float*)d_out;                 // [8,1] f32

    char* ws = (char*)d_ws;                      // proven >= 81.02 MB
    u16*   part = (u16*)(ws);                    // 8 MB partial planes
    u16*   zb1  = (u16*)(ws + (8u  << 20));      // 2 MB
    u16*   yPa  = (u16*)(ws + (12u << 20));      // 2 MB
    u16*   yPb  = (u16*)(ws + (14u << 20));      // 2 MB
    float* h1p  = (float*)(ws + (16u << 20));    // 16 KB
    u32*   ctr  = (u32*)(ws + (16u << 20) + 32768);  // 4 x u32 barrier ctrs
    u16*   Scb  = (u16*)(ws + (17u << 20));      // 32 MB
    u16*   Slb  = Scb + (size_t)NN * NN;         // 32 MB  (total 81.02 MB)

    dim3 g(NB), b(256);

    hipMemsetAsync(ctr, 0, 4 * sizeof(u32), stream);

    // Layer 1: clique, Fin=16 -> 32.  x-cvt + Sc f32 read (writes Scb).
    layer_k<16, 32, 8, 8, 1, true, true, false><<<g, b, 0, stream>>>(
        x, yPa, Sc, Scb, part, zb1, yPb, Wc1, bc1,
        Wm1, h1p, bm1, Wm2, bm2, out, ctr + 0);
    // Layer 2: clique, Fin=32 -> 16 (M=256).
    layer_k<32, 16, 4, 16, 2, false, false, false><<<g, b, 0, stream>>>(
        x, yPb, Sc, Scb, part, zb1, yPa, Wc2, bc2,
        Wm1, h1p, bm1, Wm2, bm2, out, ctr + 1);
    // Layer 3: line, Fin=16 -> 32.  Sl f32 read (writes Slb).
    layer_k<16, 32, 8, 8, 1, true, false, false><<<g, b, 0, stream>>>(
        x, yPa, Sl, Slb, part, zb1, yPb, Wl1, bl1,
        Wm1, h1p, bm1, Wm2, bm2, out, ctr + 2);
    // Layer 4: line, Fin=32 -> 16 (M=256) + MLP head.
    layer_k<32, 16, 4, 16, 2, false, false, true><<<g, b, 0, stream>>>(
        x, yPb, Sl, Slb, part, zb1, yPa, Wl2, bl2,
        Wm1, h1p, bm1, Wm2, bm2, out, ctr + 3);
}

// Round 12
// 927.071 us; speedup vs baseline: 2.1492x; 1.3426x over previous
//
#include <hip/hip_runtime.h>

// SelectionGNN clique+line. I/O: float32. Internals: bf16 end-to-end with f32
// accumulation (MFMA + reduce). B=8, N=4096, E=1, K=3, F=[16,32,16],
// MLP 65536->64->1.
// R18: persistent fusion, 3rd iteration. R17 counters (idle pipes, NO traffic
//     inflation: FETCH=79MB=essential) falsify the fence theory and point at
//     POLL CONTENTION: 512 blocks re-polling ONE agent-scope line every
//     1.7us permanently backs up the coherence point's same-line queue
//     (R16->R17: poll rate -3x -> time -1.7x, consistent).
//     Fix: (a) TREE ARRIVAL - 8 xcd-group counters (<=64 one-shot RMWs per
//     line) + 1 global counter (8 RMWs); (b) FLAG BROADCAST - grid-last
//     block's 256 threads write 512 distinct 128B-strided flags; each block
//     polls ITS OWN line (zero sharing). Monotonic values; 512KB memset once.
//     Fences unchanged from R17 (1 release + 1 acquire per block).
//     Phases = R12's verified kernels, byte-identical to R17.

#define NN 4096
#define BB 8
#define NB 512   // blocks per fused kernel

typedef unsigned short u16;
typedef unsigned int   u32;

typedef __attribute__((ext_vector_type(8))) short bf16x8;  // 8 bf16 = 4 VGPRs
typedef __attribute__((ext_vector_type(4))) float f32x4;

__device__ __forceinline__ u16 f2bf(float f) {
    union { float f; u32 i; } c; c.f = f;
    u32 i = c.i;
    u32 r = (i + 0x7FFFu + ((i >> 16) & 1u)) >> 16;  // RTNE
    return (u16)r;
}
__device__ __forceinline__ float bf2f(u16 u) {
    union { u32 i; float f; } c; c.i = ((u32)u) << 16; return c.f;
}

__device__ __forceinline__ void gload_lds16(const u16* g, u16* l) {
    __builtin_amdgcn_global_load_lds(
        (__attribute__((address_space(1))) void*)g,
        (__attribute__((address_space(3))) void*)l, 16, 0, 0);
}

// ---------------------------------------------------------------------------
// Device-scope grid barrier, contention-free form.
// Region layout (u32 indices into R): xctr[g] at g*32 (8 groups, 128B apart);
// gctr at 512; flag[b] at 1024 + b*32 (512 flags, 128B apart).
// Arrival: block -> xctr[bx>>6] (<=64 one-shot RMWs/line); 64th -> gctr
// (8 RMWs); 8th = grid-last -> broadcasts bar to all 512 flags (256 threads,
// 2 stores each, distinct lines). Poll: each block on ITS OWN flag line,
// s_sleep(32) throttle. Monotonic targets; zeroed once per launch.
// Fences: one release + one acquire per block (thread 0), as R17.
// ---------------------------------------------------------------------------
__device__ __forceinline__ void gridbar(u32* R, u32 bar) {
    __shared__ u32 gb_last;
    asm volatile("s_waitcnt vmcnt(0) lgkmcnt(0)" ::: "memory");
    __syncthreads();
    const int bx = blockIdx.x;
    if (threadIdx.x == 0) {
        __threadfence();   // release: block's writes visible device-wide
        u32 last = 0;
        u32 o = __hip_atomic_fetch_add(R + (bx >> 6) * 32, 1u,
                                       __ATOMIC_RELAXED,
                                       __HIP_MEMORY_SCOPE_AGENT);
        if (o == bar * 64 - 1) {     // group-last
            u32 g = __hip_atomic_fetch_add(R + 512, 1u, __ATOMIC_RELAXED,
                                           __HIP_MEMORY_SCOPE_AGENT);
            if (g == bar * 8 - 1) last = 1;   // grid-last
        }
        gb_last = last;
    }
    __syncthreads();
    if (gb_last) {
        for (int i = threadIdx.x; i < NB; i += 256)
            __hip_atomic_store(R + 1024 + i * 32, bar, __ATOMIC_RELAXED,
                               __HIP_MEMORY_SCOPE_AGENT);
    }
    if (threadIdx.x == 0) {
        while (__hip_atomic_load(R + 1024 + bx * 32, __ATOMIC_RELAXED,
                                 __HIP_MEMORY_SCOPE_AGENT) < bar)
            __builtin_amdgcn_s_sleep(32);
        __threadfence();   // acquire: drop stale lines before reading
    }
    __syncthreads();
}

// ---------------------------------------------------------------------------
// Phase: split-K diffusion (R12 structure). 128(M) x 64(N) tile, BK=64.
// LDS: As = L[0..24576) (3 x 8192 u16), Bs = L[24576..36864) (3 x 4096 u16).
// 3-buffer depth-2 pipeline, counted vmcnt(12/6/0) + raw s_barrier.
// ---------------------------------------------------------------------------
template <int ITERS, int MT>
__device__ void dev_diffuse(u16* L, const u16* __restrict__ Z,
                            const u16* __restrict__ S, u16* __restrict__ Part,
                            int ntR, int mtile, int kz)
{
    u16* As = L;            // 3 x 8192
    u16* Bs = L + 24576;    // 3 x 4096

    const int ntile = ((ntR & 7) << 3) | (ntR >> 3);  // XCD swizzle
    const int nBase = ntile * 64;
    const int mBase = mtile * 128;
    const int tid   = threadIdx.x;
    const int lane  = tid & 63;
    const int wv    = tid >> 6;
    const int quad  = lane >> 4;
    const int l16   = lane & 15;

    const int kStart = kz * (ITERS * 64);

    const int rl   = lane >> 3;
    const int gsl  = lane & 7;
    const int gsrc = gsl ^ rl;

    f32x4 acc[2][4];
#pragma unroll
    for (int i = 0; i < 2; ++i)
#pragma unroll
        for (int j = 0; j < 4; ++j) acc[i][j] = (f32x4){0.f, 0.f, 0.f, 0.f};

    auto stage = [&](int buf, int k0) {
#pragma unroll
        for (int j = 0; j < 4; ++j) {
            const int rb = (wv * 4 + j) * 8;   // 0..120
            gload_lds16(Z + (size_t)(mBase + rb + rl) * NN + k0 + gsrc * 8,
                        &As[buf * 8192 + rb * 64]);
        }
#pragma unroll
        for (int j = 0; j < 2; ++j) {
            const int rb = (wv * 2 + j) * 8;   // 0..56
            gload_lds16(S + (size_t)(nBase + rb + rl) * NN + k0 + gsrc * 8,
                        &Bs[buf * 4096 + rb * 64]);
        }
    };

    auto compute = [&](int buf) {
#pragma unroll
        for (int s = 0; s < 2; ++s) {
            const int g = s * 4 + quad;        // k-granule 0..7
            bf16x8 af[2], bf[4];
#pragma unroll
            for (int mi = 0; mi < 2; ++mi) {
                const int r = wv * 32 + mi * 16 + l16;
                af[mi] = *(const bf16x8*)&As[buf * 8192 + r * 64 + ((g ^ (r & 7)) << 3)];
            }
#pragma unroll
            for (int ni = 0; ni < 4; ++ni) {
                const int r = ni * 16 + l16;
                bf[ni] = *(const bf16x8*)&Bs[buf * 4096 + r * 64 + ((g ^ (r & 7)) << 3)];
            }
#pragma unroll
            for (int mi = 0; mi < 2; ++mi)
#pragma unroll
                for (int ni = 0; ni < 4; ++ni)
                    acc[mi][ni] = __builtin_amdgcn_mfma_f32_16x16x32_bf16(
                        af[mi], bf[ni], acc[mi][ni], 0, 0, 0);
        }
    };

    stage(0, kStart);
    stage(1, kStart + 64);

#pragma unroll
    for (int i = 0; i < ITERS; ++i) {
        if (i + 2 < ITERS) stage((i + 2) % 3, kStart + (i + 2) * 64);
        if (i < ITERS - 2)
            asm volatile("s_waitcnt vmcnt(12)" ::: "memory");
        else if (i == ITERS - 2)
            asm volatile("s_waitcnt vmcnt(6)" ::: "memory");
        else
            asm volatile("s_waitcnt vmcnt(0)" ::: "memory");
        __builtin_amdgcn_s_barrier();
        compute(i % 3);
        if (i + 1 < ITERS) __builtin_amdgcn_s_barrier();
    }

    asm volatile("s_waitcnt lgkmcnt(0)" ::: "memory");
    __builtin_amdgcn_s_barrier();

    // Per-wave transpose: 32 rows x 72 u16; D: col=lane&15, row=quad*4+i.
    u16* tb = &As[wv * 2304];
#pragma unroll
    for (int mi = 0; mi < 2; ++mi)
#pragma unroll
        for (int ni = 0; ni < 4; ++ni)
#pragma unroll
            for (int i = 0; i < 4; ++i)
                tb[(mi * 16 + quad * 4 + i) * 72 + ni * 16 + l16] =
                    f2bf(acc[mi][ni][i]);

    const size_t plane = (size_t)MT * 128 * NN;
    u16* pp = Part + (size_t)kz * plane;
    const int row0g = mBase + wv * 32;
#pragma unroll
    for (int j = 0; j < 4; ++j) {
        const int r = (lane >> 3) + j * 8;      // 0..31
        const int c = (lane & 7) * 8;           // 0..56
        bf16x8 v = *(const bf16x8*)&tb[r * 72 + c];
        *(bf16x8*)&pp[(size_t)(row0g + r) * NN + nBase + c] = v;
    }
}

// ---------------------------------------------------------------------------
// Phase: diffusion with FUSED f32 S conversion (R12 cvtB; M=128, mBase=0).
// LDS: As = L[0..16384) (2 x 8192), Bs = L[16384..24576) (2 x 4096).
// ---------------------------------------------------------------------------
template <int ITERS>
__device__ void dev_cvtB(u16* L, const u16* __restrict__ Z,
                         const float* __restrict__ Sf, u16* __restrict__ Part,
                         u16* __restrict__ Sb, int ntR, int kz)
{
    u16* As = L;            // 2 x 8192
    u16* Bs = L + 16384;    // 2 x 4096

    const int ntile = ((ntR & 7) << 3) | (ntR >> 3);
    const int nBase = ntile * 64;
    const int tid   = threadIdx.x;
    const int lane  = tid & 63;
    const int wv    = tid >> 6;
    const int quad  = lane >> 4;
    const int l16   = lane & 15;

    const int kStart = kz * (ITERS * 64);

    const int rl   = lane >> 3;
    const int gsl  = lane & 7;
    const int gsrc = gsl ^ rl;

    f32x4 acc[2][4];
#pragma unroll
    for (int i = 0; i < 2; ++i)
#pragma unroll
        for (int j = 0; j < 4; ++j) acc[i][j] = (f32x4){0.f, 0.f, 0.f, 0.f};

    auto stageA = [&](int buf, int k0) {
#pragma unroll
        for (int j = 0; j < 4; ++j) {
            const int rb = (wv * 4 + j) * 8;
            gload_lds16(Z + (size_t)(rb + rl) * NN + k0 + gsrc * 8,
                        &As[buf * 8192 + rb * 64]);
        }
    };

    float4 fB[2][2];
    auto loadB = [&](int k0) {
#pragma unroll
        for (int j = 0; j < 2; ++j) {
            const int row = nBase + (wv * 2 + j) * 8 + rl;
            const float* p = Sf + (size_t)row * NN + k0 + gsrc * 8;
            fB[j][0] = *(const float4*)p;
            fB[j][1] = *(const float4*)(p + 4);
        }
    };
    auto writeB = [&](int buf, int k0) {
#pragma unroll
        for (int j = 0; j < 2; ++j) {
            const int rloc = (wv * 2 + j) * 8 + rl;       // 0..63
            bf16x8 v;
            v[0] = (short)f2bf(fB[j][0].x); v[1] = (short)f2bf(fB[j][0].y);
            v[2] = (short)f2bf(fB[j][0].z); v[3] = (short)f2bf(fB[j][0].w);
            v[4] = (short)f2bf(fB[j][1].x); v[5] = (short)f2bf(fB[j][1].y);
            v[6] = (short)f2bf(fB[j][1].z); v[7] = (short)f2bf(fB[j][1].w);
            *(bf16x8*)&Bs[buf * 4096 + rloc * 64 + gsl * 8] = v;
            *(bf16x8*)&Sb[(size_t)(nBase + rloc) * NN + k0 + gsrc * 8] = v;
        }
    };

    auto compute = [&](int buf) {
#pragma unroll
        for (int s = 0; s < 2; ++s) {
            const int g = s * 4 + quad;
            bf16x8 af[2], bf[4];
#pragma unroll
            for (int mi = 0; mi < 2; ++mi) {
                const int r = wv * 32 + mi * 16 + l16;
                af[mi] = *(const bf16x8*)&As[buf * 8192 + r * 64 + ((g ^ (r & 7)) << 3)];
            }
#pragma unroll
            for (int ni = 0; ni < 4; ++ni) {
                const int r = ni * 16 + l16;
                bf[ni] = *(const bf16x8*)&Bs[buf * 4096 + r * 64 + ((g ^ (r & 7)) << 3)];
            }
#pragma unroll
            for (int mi = 0; mi < 2; ++mi)
#pragma unroll
                for (int ni = 0; ni < 4; ++ni)
                    acc[mi][ni] = __builtin_amdgcn_mfma_f32_16x16x32_bf16(
                        af[mi], bf[ni], acc[mi][ni], 0, 0, 0);
        }
    };

    loadB(kStart);
    stageA(0, kStart);
    writeB(0, kStart);
    __syncthreads();

#pragma unroll
    for (int i = 0; i < ITERS; ++i) {
        const int cur = i & 1;
        if (i + 1 < ITERS) {
            stageA(cur ^ 1, kStart + (i + 1) * 64);
            loadB(kStart + (i + 1) * 64);
        }
        compute(cur);
        if (i + 1 < ITERS) writeB(cur ^ 1, kStart + (i + 1) * 64);
        __syncthreads();
    }

    u16* tb = &As[wv * 2304];
#pragma unroll
    for (int mi = 0; mi < 2; ++mi)
#pragma unroll
        for (int ni = 0; ni < 4; ++ni)
#pragma unroll
            for (int i = 0; i < 4; ++i)
                tb[(mi * 16 + quad * 4 + i) * 72 + ni * 16 + l16] =
                    f2bf(acc[mi][ni][i]);

    const size_t plane = (size_t)128 * NN;
    u16* pp = Part + (size_t)kz * plane;
    const int row0g = wv * 32;
#pragma unroll
    for (int j = 0; j < 4; ++j) {
        const int r = (lane >> 3) + j * 8;
        const int c = (lane & 7) * 8;
        bf16x8 v = *(const bf16x8*)&tb[r * 72 + c];
        *(bf16x8*)&pp[(size_t)(row0g + r) * NN + nBase + c] = v;
    }
}

// ---------------------------------------------------------------------------
// Phase: sum KS bf16 partial planes -> bf16 z (grid-stride over NB blocks).
// ---------------------------------------------------------------------------
template <int KS>
__device__ void dev_reduce(const u16* __restrict__ part, int planeElems,
                           u16* __restrict__ outb)
{
    const int base   = (blockIdx.x * 256 + threadIdx.x) * 8;
    const int stride = NB * 256 * 8;
    for (int i = base; i < planeElems; i += stride) {
        float s[8];
#pragma unroll
        for (int e = 0; e < 8; ++e) s[e] = 0.f;
#pragma unroll
        for (int p = 0; p < KS; ++p) {
            uint4 v = *(const uint4*)(part + (size_t)p * planeElems + i);
            const u32 w[4] = {v.x, v.y, v.z, v.w};
#pragma unroll
            for (int q = 0; q < 4; ++q) {
                union { u32 i; float f; } lo, hi;
                lo.i = w[q] << 16;
                hi.i = w[q] & 0xFFFF0000u;
                s[q * 2]     += lo.f;
                s[q * 2 + 1] += hi.f;
            }
        }
        uint4 o;
        o.x = (u32)f2bf(s[0]) | ((u32)f2bf(s[1]) << 16);
        o.y = (u32)f2bf(s[2]) | ((u32)f2bf(s[3]) << 16);
        o.z = (u32)f2bf(s[4]) | ((u32)f2bf(s[5]) << 16);
        o.w = (u32)f2bf(s[6]) | ((u32)f2bf(s[7]) << 16);
        *(uint4*)(outb + i) = o;
    }
}

// ---------------------------------------------------------------------------
// Phase: tap combine + ReLU (blocks 0..127 do work; all blocks return).
// ---------------------------------------------------------------------------
template <int FIN, int FOUT, int KS>
__device__ void dev_combine(u16* L, const u16* __restrict__ z0,
                            const u16* __restrict__ z1,
                            const u16* __restrict__ part2, int planeElems,
                            const float* __restrict__ W,
                            const float* __restrict__ bias,
                            u16* __restrict__ out)
{
    float* hs = (float*)L;
    float* bs = hs + FOUT * 3 * FIN;
    for (int i = threadIdx.x; i < FOUT * 3 * FIN; i += 256) hs[i] = W[i];
    if (threadIdx.x < FOUT) bs[threadIdx.x] = bias[threadIdx.x];
    __syncthreads();

    const int b = blockIdx.x >> 4;                      // nb = 16
    const int n = (blockIdx.x & 15) * 256 + threadIdx.x;

    float zv[3][FIN];
    const u16* zp0 = z0 + (size_t)b * FIN * NN + n;
    const u16* zp1 = z1 + (size_t)b * FIN * NN + n;
    const u16* zp2 = part2 + (size_t)b * FIN * NN + n;
#pragma unroll
    for (int f = 0; f < FIN; ++f) {
        zv[0][f] = bf2f(zp0[(size_t)f * NN]);
        zv[1][f] = bf2f(zp1[(size_t)f * NN]);
        float s = 0.f;
#pragma unroll
        for (int p = 0; p < KS; ++p)
            s += bf2f(zp2[(size_t)p * planeElems + (size_t)f * NN]);
        zv[2][f] = s;
    }

    u16* op = out + (size_t)b * FOUT * NN + n;
    for (int g = 0; g < FOUT; ++g) {
        float acc = bs[g];
#pragma unroll
        for (int k = 0; k < 3; ++k)
#pragma unroll
            for (int f = 0; f < FIN; ++f)
                acc = fmaf(hs[(g * 3 + k) * FIN + f], zv[k][f], acc);
        op[(size_t)g * NN] = f2bf(fmaxf(acc, 0.f));
    }
}

// ---------------------------------------------------------------------------
// Phase: MLP layer 1 split-K (NB blocks: j = bx&63, slice = bx>>6).
// ---------------------------------------------------------------------------
__device__ void dev_mlp1(u16* L, const u16* __restrict__ y,
                         const float* __restrict__ Wm1, float* __restrict__ h1p)
{
    const int j     = blockIdx.x & 63;
    const int slice = blockIdx.x >> 6;
    const int base  = slice * 8192;
    const int D     = 16 * NN;  // 65536

    float acc[BB];
#pragma unroll
    for (int b = 0; b < BB; ++b) acc[b] = 0.f;

    const float* wrow = Wm1 + (size_t)j * D + base;
    for (int idx = threadIdx.x * 8; idx < 8192; idx += 256 * 8) {
        float4 w0 = *(const float4*)(wrow + idx);
        float4 w1 = *(const float4*)(wrow + idx + 4);
#pragma unroll
        for (int b = 0; b < BB; ++b) {
            uint4 yv = *(const uint4*)(y + (size_t)b * D + base + idx);
            union { u32 i; float f; } c[8];
            c[0].i = yv.x << 16; c[1].i = yv.x & 0xFFFF0000u;
            c[2].i = yv.y << 16; c[3].i = yv.y & 0xFFFF0000u;
            c[4].i = yv.z << 16; c[5].i = yv.z & 0xFFFF0000u;
            c[6].i = yv.w << 16; c[7].i = yv.w & 0xFFFF0000u;
            acc[b] = fmaf(w0.x, c[0].f, acc[b]);
            acc[b] = fmaf(w0.y, c[1].f, acc[b]);
            acc[b] = fmaf(w0.z, c[2].f, acc[b]);
            acc[b] = fmaf(w0.w, c[3].f, acc[b]);
            acc[b] = fmaf(w1.x, c[4].f, acc[b]);
            acc[b] = fmaf(w1.y, c[5].f, acc[b]);
            acc[b] = fmaf(w1.z, c[6].f, acc[b]);
            acc[b] = fmaf(w1.w, c[7].f, acc[b]);
        }
    }

    float* red = (float*)L;   // [BB][4]
    const int lane = threadIdx.x & 63;
    const int w    = threadIdx.x >> 6;
#pragma unroll
    for (int b = 0; b < BB; ++b) {
        float v = acc[b];
        for (int off = 32; off > 0; off >>= 1) v += __shfl_down(v, off, 64);
        if (lane == 0) red[b * 4 + w] = v;
    }
    __syncthreads();
    if (threadIdx.x < BB) {
        const int b = threadIdx.x;
        h1p[slice * (BB * 64) + b * 64 + j] =
            red[b * 4 + 0] + red[b * 4 + 1] + red[b * 4 + 2] + red[b * 4 + 3];
    }
}

// ---------------------------------------------------------------------------
// Phase: MLP layer 2 (+ slice-sum + bias/ReLU). Block 0, lanes 0..63.
// ---------------------------------------------------------------------------
__device__ void dev_mlp2(const float* __restrict__ h1p,
                         const float* __restrict__ bm1,
                         const float* __restrict__ Wm2,
                         const float* __restrict__ bm2, float* __restrict__ out)
{
    if (threadIdx.x >= 64) return;
    const int lane = threadIdx.x;
    const float w    = Wm2[lane];
    const float b1   = bm1[lane];
    const float bias = bm2[0];
    for (int b = 0; b < BB; ++b) {
        float h = 0.f;
#pragma unroll
        for (int p = 0; p < 8; ++p) h += h1p[p * (BB * 64) + b * 64 + lane];
        float v = fmaxf(h + b1, 0.f) * w;
        for (int off = 32; off > 0; off >>= 1) v += __shfl_down(v, off, 64);
        if (lane == 0) out[b] = v + bias;
    }
}

// ---------------------------------------------------------------------------
// One GNN layer as a persistent kernel. NB=512 blocks x 256 threads, 72 KB
// LDS, __launch_bounds__(256,2) -> 2 blocks/CU x 256 CU, all co-resident
// (proven by R16/R17 correct completion).
// Phases: [DO_X: x f32->bf16] -> diffuse1 (CVTB: fused S-convert) -> reduce
// -> diffuse2 -> combine -> [DO_MLP: mlp1 -> mlp2], separated by gridbar.
// ---------------------------------------------------------------------------
template <int FIN, int FOUT, int KS, int ITERS, int MT,
          bool CVTB, bool DO_X, bool DO_MLP>
__global__ __launch_bounds__(256, 2) void layer_k(
    const float* xf, u16* zio, const float* Sf, u16* Sb,
    u16* part, u16* zb1, u16* zout,
    const float* W, const float* bias,
    const float* Wm1, float* h1p, const float* bm1,
    const float* Wm2, const float* bm2, float* outp, u32* bar)
{
    __shared__ __align__(16) u16 L[36864];   // 72 KB
    const int bx   = blockIdx.x;
    const int ntR  = bx & 63;
    const int rest = bx >> 6;
    const int mtile = rest & (MT - 1);
    const int kz    = rest / MT;
    const int planeElems = MT * 128 * NN;
    u32 bi = 0;

    if constexpr (DO_X) {
        // NB blocks x 256 thr x 4 floats = 524288 = |x| exactly.
        const int i = (bx * 256 + threadIdx.x) * 4;
        float4 v = *(const float4*)(xf + i);
        ushort4 o;
        o.x = f2bf(v.x); o.y = f2bf(v.y); o.z = f2bf(v.z); o.w = f2bf(v.w);
        *(ushort4*)(zio + i) = o;
        gridbar(bar, ++bi);
    }

    if constexpr (CVTB)
        dev_cvtB<ITERS>(L, zio, Sf, part, Sb, ntR, kz);
    else
        dev_diffuse<ITERS, MT>(L, zio, Sb, part, ntR, mtile, kz);
    gridbar(bar, ++bi);

    dev_reduce<KS>(part, planeElems, zb1);
    gridbar(bar, ++bi);

    dev_diffuse<ITERS, MT>(L, zb1, Sb, part, ntR, mtile, kz);
    gridbar(bar, ++bi);

    if (bx < 128)
        dev_combine<FIN, FOUT, KS>(L, zio, zb1, part, planeElems, W, bias, zout);

    if constexpr (DO_MLP) {
        gridbar(bar, ++bi);
        dev_mlp1(L, zout, Wm1, h1p);
        gridbar(bar, ++bi);
        if (bx == 0) dev_mlp2(h1p, bm1, Wm2, bm2, outp);
    }
}

// ---------------------------------------------------------------------------
extern "C" void kernel_launch(void* const* d_in, const int* in_sizes, int n_in,
                              void* d_out, int out_size, void* d_ws, size_t ws_size,
                              hipStream_t stream)
{
    const float* x   = (const float*)d_in[0];   // [8,16,4096]
    const float* Sc  = (const float*)d_in[1];   // [1,4096,4096]
    const float* Sl  = (const float*)d_in[2];   // [1,4096,4096]
    const float* Wc1 = (const float*)d_in[3];
    const float* bc1 = (const float*)d_in[4];
    const float* Wc2 = (const float*)d_in[5];
    const float* bc2 = (const float*)d_in[6];
    const float* Wl1 = (const float*)d_in[7];
    const float* bl1 = (const float*)d_in[8];
    const float* Wl2 = (const float*)d_in[9];
    const float* bl2 = (const float*)d_in[10];
    const float* Wm1 = (const float*)d_in[11];  // [64,65536]
    const float* bm1 = (const float*)d_in[12];
    const float* Wm2 = (const float*)d_in[13];  // [1,64]
    const float* bm2 = (const float*)d_in[14];
    float* out = (float*)d_out;                 // [8,1] f32

    char* ws = (char*)d_ws;                      // proven >= 81.02 MB
    u16*   part = (u16*)(ws);                    // 8 MB partial planes
    u16*   zb1  = (u16*)(ws + (8u  << 20));      // 2 MB
    u16*   yPa  = (u16*)(ws + (12u << 20));      // 2 MB
    u16*   yPb  = (u16*)(ws + (14u << 20));      // 2 MB
    float* h1p  = (float*)(ws + (16u << 20));    // 16 KB
    u32*   barR = (u32*)(ws + (16u << 20) + (128u << 10));  // 4 x 128 KB
    u16*   Scb  = (u16*)(ws + (17u << 20));      // 32 MB
    u16*   Slb  = Scb + (size_t)NN * NN;         // 32 MB  (total 81.02 MB)

    dim3 g(NB), b(256);

    hipMemsetAsync(barR, 0, 4 * (128u << 10), stream);   // all ctrs + flags

    const u32 RSTR = (128u << 10) / 4;   // 32768 u32 per kernel region

    // Layer 1: clique, Fin=16 -> 32.  x-cvt + Sc f32 read (writes Scb).
    layer_k<16, 32, 8, 8, 1, true, true, false><<<g, b, 0, stream>>>(
        x, yPa, Sc, Scb, part, zb1, yPb, Wc1, bc1,
        Wm1, h1p, bm1, Wm2, bm2, out, barR + 0 * RSTR);
    // Layer 2: clique, Fin=32 -> 16 (M=256).
    layer_k<32, 16, 4, 16, 2, false, false, false><<<g, b, 0, stream>>>(
        x, yPb, Sc, Scb, part, zb1, yPa, Wc2, bc2,
        Wm1, h1p, bm1, Wm2, bm2, out, barR + 1 * RSTR);
    // Layer 3: line, Fin=16 -> 32.  Sl f32 read (writes Slb).
    layer_k<16, 32, 8, 8, 1, true, false, false><<<g, b, 0, stream>>>(
        x, yPa, Sl, Slb, part, zb1, yPb, Wl1, bl1,
        Wm1, h1p, bm1, Wm2, bm2, out, barR + 2 * RSTR);
    // Layer 4: line, Fin=32 -> 16 (M=256) + MLP head.
    layer_k<32, 16, 4, 16, 2, false, false, true><<<g, b, 0, stream>>>(
        x, yPb, Sl, Slb, part, zb1, yPa, Wl2, bl2,
        Wm1, h1p, bm1, Wm2, bm2, out, barR + 3 * RSTR);
}

// Round 13
// 367.190 us; speedup vs baseline: 5.4263x; 2.5248x over previous
//
#include <hip/hip_runtime.h>

// SelectionGNN clique+line. I/O: float32. Internals: bf16 end-to-end with f32
// accumulation (MFMA + reduce). B=8, N=4096, E=1, K=3, F=[16,32,16],
// MLP 65536->64->1.
// R19: REVERT to R15 (best verified: 367.3 us). The persistent-fusion family
//     (R14/R16/R17/R18) is abandoned: three successive barrier redesigns
//     measured 594 -> 345 -> 237 us/layer vs ~80 us of work -- device-side
//     grid barriers on MI355X cost ~30 us/crossing vs ~2.4 us/dispatch for
//     hardware launches (R7 measurement). Evidence across the session
//     (R12 small-tile == R15 big-tile == ~367-368 us; cvt pinned at ~60 us
//     across 4 schedules) indicates the pipeline is bound by mixed-stream
//     S-panel traffic (~1 GB at ~3.5 TB/s effective) + ~50 us dispatch
//     serialization; remaining levers have modeled gains below risk.
//     This file is byte-identical to R15.

#define NN 4096
#define BB 8

typedef unsigned short u16;
typedef unsigned int   u32;

typedef __attribute__((ext_vector_type(8))) short bf16x8;  // 8 bf16 = 4 VGPRs
typedef __attribute__((ext_vector_type(4))) float f32x4;

__device__ __forceinline__ u16 f2bf(float f) {
    union { float f; u32 i; } c; c.f = f;
    u32 i = c.i;
    u32 r = (i + 0x7FFFu + ((i >> 16) & 1u)) >> 16;  // RTNE
    return (u16)r;
}
__device__ __forceinline__ float bf2f(u16 u) {
    union { u32 i; float f; } c; c.i = ((u32)u) << 16; return c.f;
}
__device__ __forceinline__ u32 pack2bf(float lo, float hi) {
    return (u32)f2bf(lo) | ((u32)f2bf(hi) << 16);
}

__device__ __forceinline__ void gload_lds16(const u16* g, u16* l) {
    __builtin_amdgcn_global_load_lds(
        (__attribute__((address_space(1))) void*)g,
        (__attribute__((address_space(3))) void*)l, 16, 0, 0);
}

// ---------------------------------------------------------------------------
// x: 524288 f32 -> bf16. 256 blocks x 256 threads x 8 floats, one shot.
// ---------------------------------------------------------------------------
__global__ __launch_bounds__(256) void cvt_x(const float* __restrict__ in,
                                             u16* __restrict__ out)
{
    const int i = (blockIdx.x * 256 + threadIdx.x) * 8;
    float4 a = *(const float4*)(in + i);
    float4 b = *(const float4*)(in + i + 4);
    uint4 o;
    o.x = pack2bf(a.x, a.y); o.y = pack2bf(a.z, a.w);
    o.z = pack2bf(b.x, b.y); o.w = pack2bf(b.z, b.w);
    *(uint4*)(out + i) = o;
}

// ---------------------------------------------------------------------------
// Split-K diffusion, 128(M) x 128(N) tile, BK=64, bf16 A/B via async LDS:
//   Part[kz][r,n] = sum_{k in slice} Z[r,k] * S[n,k]   (bf16 partial planes)
// LDS 96 KB: A = L[0..24576) u16 (3 x 8192), B = L[24576..49152) (3 x 8192).
// XOR-swizzled 16B granules: slot(r,g) = g ^ (r&7).
// 4 waves in 2x2; wave owns 64x64 via 4x4 mfma frags: per interval 32 MFMA,
// 16 ds_read_b128, 8 gload_lds (2:1 MFMA:ds).
// Schedule: stage(0); stage(1); per iter i:
//   [stage(i+2)] ; s_waitcnt vmcnt(16|8|0) ; s_barrier ; compute(i) ;
//   [s_barrier]. Counted vmcnt keeps 2 staged tiles in flight (T4).
// grid: (32, M/128, KS). Epilogue: per-wave LDS transpose (64 x 72 u16) ->
// 8x global b128 stores per lane.
// ---------------------------------------------------------------------------
template <int ITERS>
__global__ __launch_bounds__(256) void diffuse(const u16* __restrict__ Z,
                                               const u16* __restrict__ S,
                                               u16* __restrict__ Part)
{
    __shared__ u16 L[6 * 8192];   // 96 KB

    const int bx    = blockIdx.x;                   // 0..31
    const int ntile = ((bx & 7) << 2) | (bx >> 3);  // XCD swizzle
    const int nBase = ntile * 128;
    const int mBase = blockIdx.y * 128;
    const int tid   = threadIdx.x;
    const int lane  = tid & 63;
    const int wv    = tid >> 6;
    const int quad  = lane >> 4;
    const int l16   = lane & 15;
    const int wr    = (wv >> 1) * 64;   // wave row offset in tile
    const int wc    = (wv & 1) * 64;    // wave col offset in tile

    const int kStart = (int)blockIdx.z * (ITERS * 64);

    // async staging: wave-issue = 64 lanes x 16 B = 8 rows x 8 granules
    const int rl   = lane >> 3;
    const int gsl  = lane & 7;
    const int gsrc = gsl ^ rl;

    f32x4 acc[4][4];
#pragma unroll
    for (int i = 0; i < 4; ++i)
#pragma unroll
        for (int j = 0; j < 4; ++j) acc[i][j] = (f32x4){0.f, 0.f, 0.f, 0.f};

    auto stage = [&](int buf, int k0) {
#pragma unroll
        for (int j = 0; j < 4; ++j) {
            const int rb = wv * 32 + j * 8;    // wave's 32 rows of each tile
            gload_lds16(Z + (size_t)(mBase + rb + rl) * NN + k0 + gsrc * 8,
                        &L[buf * 8192 + rb * 64]);
            gload_lds16(S + (size_t)(nBase + rb + rl) * NN + k0 + gsrc * 8,
                        &L[24576 + buf * 8192 + rb * 64]);
        }
    };

    auto compute = [&](int buf) {
#pragma unroll
        for (int s = 0; s < 2; ++s) {
            const int g = s * 4 + quad;        // k-granule 0..7
            bf16x8 af[4], bf[4];
#pragma unroll
            for (int mi = 0; mi < 4; ++mi) {
                const int r = wr + mi * 16 + l16;
                af[mi] = *(const bf16x8*)&L[buf * 8192 + r * 64 + ((g ^ (r & 7)) << 3)];
            }
#pragma unroll
            for (int ni = 0; ni < 4; ++ni) {
                const int r = wc + ni * 16 + l16;
                bf[ni] = *(const bf16x8*)&L[24576 + buf * 8192 + r * 64 + ((g ^ (r & 7)) << 3)];
            }
#pragma unroll
            for (int mi = 0; mi < 4; ++mi)
#pragma unroll
                for (int ni = 0; ni < 4; ++ni)
                    acc[mi][ni] = __builtin_amdgcn_mfma_f32_16x16x32_bf16(
                        af[mi], bf[ni], acc[mi][ni], 0, 0, 0);
        }
    };

    // prologue: two tiles in flight before first wait
    stage(0, kStart);
    stage(1, kStart + 64);

#pragma unroll
    for (int i = 0; i < ITERS; ++i) {
        if (i + 2 < ITERS) stage((i + 2) % 3, kStart + (i + 2) * 64);
        if (i < ITERS - 2)
            asm volatile("s_waitcnt vmcnt(16)" ::: "memory");  // stage(i) landed
        else if (i == ITERS - 2)
            asm volatile("s_waitcnt vmcnt(8)" ::: "memory");
        else
            asm volatile("s_waitcnt vmcnt(0)" ::: "memory");
        __builtin_amdgcn_s_barrier();          // raw barrier: no vmcnt drain
        compute(i % 3);
        if (i + 1 < ITERS) __builtin_amdgcn_s_barrier();  // guard buf reuse
    }

    // All LDS reads done before reusing L as scratch.
    asm volatile("s_waitcnt lgkmcnt(0)" ::: "memory");
    __builtin_amdgcn_s_barrier();

    // Per-wave transpose region: 64 rows x 72 u16 (144B rows, 16B-aligned).
    // D mapping: col = lane&15, row = quad*4 + reg.
    u16* tb = &L[wv * 4608];
#pragma unroll
    for (int mi = 0; mi < 4; ++mi)
#pragma unroll
        for (int ni = 0; ni < 4; ++ni)
#pragma unroll
            for (int i = 0; i < 4; ++i)
                tb[(mi * 16 + quad * 4 + i) * 72 + ni * 16 + l16] =
                    f2bf(acc[mi][ni][i]);

    const size_t plane = (size_t)gridDim.y * 128 * NN;
    u16* pp = Part + (size_t)blockIdx.z * plane;
    const int row0g = mBase + wr;
    const int col0g = nBase + wc;
#pragma unroll
    for (int j = 0; j < 8; ++j) {
        const int r = (lane >> 3) + j * 8;      // 0..63
        const int c = (lane & 7) * 8;           // 0..56
        bf16x8 v = *(const bf16x8*)&tb[r * 72 + c];
        *(bf16x8*)&pp[(size_t)(row0g + r) * NN + col0g + c] = v;
    }
}

// ---------------------------------------------------------------------------
// Same tile geometry with FUSED S conversion (first pass over each S):
// B read in f32 (reg-staged), packed to bf16, ds_write into the swizzled
// slots AND written through to Sb. 2-buffer __syncthreads pipeline (2 one-off
// dispatches; R13-verified logic).
// ---------------------------------------------------------------------------
template <int ITERS>
__global__ __launch_bounds__(256) void diffuse_cvtB(const u16* __restrict__ Z,
                                                    const float* __restrict__ Sf,
                                                    u16* __restrict__ Part,
                                                    u16* __restrict__ Sb)
{
    __shared__ u16 L[4 * 8192];   // 64 KB: A 2x8192 @0, B 2x8192 @16384

    const int bx    = blockIdx.x;
    const int ntile = ((bx & 7) << 2) | (bx >> 3);
    const int nBase = ntile * 128;
    const int mBase = blockIdx.y * 128;
    const int tid   = threadIdx.x;
    const int lane  = tid & 63;
    const int wv    = tid >> 6;
    const int quad  = lane >> 4;
    const int l16   = lane & 15;
    const int wr    = (wv >> 1) * 64;
    const int wc    = (wv & 1) * 64;

    const int kStart = (int)blockIdx.z * (ITERS * 64);

    const int rl   = lane >> 3;
    const int gsl  = lane & 7;
    const int gsrc = gsl ^ rl;

    f32x4 acc[4][4];
#pragma unroll
    for (int i = 0; i < 4; ++i)
#pragma unroll
        for (int j = 0; j < 4; ++j) acc[i][j] = (f32x4){0.f, 0.f, 0.f, 0.f};

    auto stageA = [&](int buf, int k0) {
#pragma unroll
        for (int j = 0; j < 4; ++j) {
            const int rb = wv * 32 + j * 8;
            gload_lds16(Z + (size_t)(mBase + rb + rl) * NN + k0 + gsrc * 8,
                        &L[buf * 8192 + rb * 64]);
        }
    };

    float4 fB[4][2];
    auto loadB = [&](int k0) {
#pragma unroll
        for (int j = 0; j < 4; ++j) {
            const int row = nBase + wv * 32 + j * 8 + rl;
            const float* p = Sf + (size_t)row * NN + k0 + gsrc * 8;
            fB[j][0] = *(const float4*)p;
            fB[j][1] = *(const float4*)(p + 4);
        }
    };
    auto writeB = [&](int buf, int k0) {
#pragma unroll
        for (int j = 0; j < 4; ++j) {
            const int rloc = wv * 32 + j * 8 + rl;        // 0..127 within tile
            bf16x8 v;
            v[0] = (short)f2bf(fB[j][0].x); v[1] = (short)f2bf(fB[j][0].y);
            v[2] = (short)f2bf(fB[j][0].z); v[3] = (short)f2bf(fB[j][0].w);
            v[4] = (short)f2bf(fB[j][1].x); v[5] = (short)f2bf(fB[j][1].y);
            v[6] = (short)f2bf(fB[j][1].z); v[7] = (short)f2bf(fB[j][1].w);
            *(bf16x8*)&L[16384 + buf * 8192 + rloc * 64 + gsl * 8] = v;
            *(bf16x8*)&Sb[(size_t)(nBase + rloc) * NN + k0 + gsrc * 8] = v;
        }
    };

    auto compute = [&](int buf) {
#pragma unroll
        for (int s = 0; s < 2; ++s) {
            const int g = s * 4 + quad;
            bf16x8 af[4], bf[4];
#pragma unroll
            for (int mi = 0; mi < 4; ++mi) {
                const int r = wr + mi * 16 + l16;
                af[mi] = *(const bf16x8*)&L[buf * 8192 + r * 64 + ((g ^ (r & 7)) << 3)];
            }
#pragma unroll
            for (int ni = 0; ni < 4; ++ni) {
                const int r = wc + ni * 16 + l16;
                bf[ni] = *(const bf16x8*)&L[16384 + buf * 8192 + r * 64 + ((g ^ (r & 7)) << 3)];
            }
#pragma unroll
            for (int mi = 0; mi < 4; ++mi)
#pragma unroll
                for (int ni = 0; ni < 4; ++ni)
                    acc[mi][ni] = __builtin_amdgcn_mfma_f32_16x16x32_bf16(
                        af[mi], bf[ni], acc[mi][ni], 0, 0, 0);
        }
    };

    loadB(kStart);
    stageA(0, kStart);
    writeB(0, kStart);
    __syncthreads();

#pragma unroll
    for (int i = 0; i < ITERS; ++i) {
        const int k1 = kStart + (i + 1) * 64;
        if (i + 1 < ITERS) { stageA((i + 1) & 1, k1); loadB(k1); }
        compute(i & 1);
        if (i + 1 < ITERS) writeB((i + 1) & 1, k1);
        __syncthreads();
    }

    u16* tb = &L[wv * 4608];
#pragma unroll
    for (int mi = 0; mi < 4; ++mi)
#pragma unroll
        for (int ni = 0; ni < 4; ++ni)
#pragma unroll
            for (int i = 0; i < 4; ++i)
                tb[(mi * 16 + quad * 4 + i) * 72 + ni * 16 + l16] =
                    f2bf(acc[mi][ni][i]);

    const size_t plane = (size_t)gridDim.y * 128 * NN;
    u16* pp = Part + (size_t)blockIdx.z * plane;
    const int row0g = mBase + wr;
    const int col0g = nBase + wc;
#pragma unroll
    for (int j = 0; j < 8; ++j) {
        const int r = (lane >> 3) + j * 8;
        const int c = (lane & 7) * 8;
        bf16x8 v = *(const bf16x8*)&tb[r * 72 + c];
        *(bf16x8*)&pp[(size_t)(row0g + r) * NN + col0g + c] = v;
    }
}

// ---------------------------------------------------------------------------
// Sum KS bf16 partial planes (f32 accumulate) -> bf16 z.  (z1 only.)
// ---------------------------------------------------------------------------
template <int KS>
__global__ __launch_bounds__(256) void reduce_part(const u16* __restrict__ part,
                                                   int planeElems,
                                                   u16* __restrict__ outb)
{
    const int base   = (blockIdx.x * 256 + threadIdx.x) * 8;
    const int stride = gridDim.x * 256 * 8;
    for (int i = base; i < planeElems; i += stride) {
        float s[8];
#pragma unroll
        for (int e = 0; e < 8; ++e) s[e] = 0.f;
#pragma unroll
        for (int p = 0; p < KS; ++p) {
            uint4 v = *(const uint4*)(part + (size_t)p * planeElems + i);
            const u32 w[4] = {v.x, v.y, v.z, v.w};
#pragma unroll
            for (int q = 0; q < 4; ++q) {
                union { u32 i; float f; } lo, hi;
                lo.i = w[q] << 16;
                hi.i = w[q] & 0xFFFF0000u;
                s[q * 2]     += lo.f;
                s[q * 2 + 1] += hi.f;
            }
        }
        uint4 o;
        o.x = (u32)f2bf(s[0]) | ((u32)f2bf(s[1]) << 16);
        o.y = (u32)f2bf(s[2]) | ((u32)f2bf(s[3]) << 16);
        o.z = (u32)f2bf(s[4]) | ((u32)f2bf(s[5]) << 16);
        o.w = (u32)f2bf(s[6]) | ((u32)f2bf(s[7]) << 16);
        *(uint4*)(outb + i) = o;
    }
}

// ---------------------------------------------------------------------------
// Tap combine + ReLU, bf16 in/out (f32 math). Tap 2 read directly from the
// KS bf16 partial planes (fused reduce):
// out[b,g,n] = relu( bias[g] + sum_k sum_f W[g,k,f] * z_k[b,f,n] )
// ---------------------------------------------------------------------------
template <int FIN, int FOUT, int KS>
__global__ __launch_bounds__(256) void combine_relu(
    const u16* __restrict__ z0, const u16* __restrict__ z1,
    const u16* __restrict__ part2, int planeElems,
    const float* __restrict__ W, const float* __restrict__ bias,
    u16* __restrict__ out)
{
    __shared__ float hs[FOUT * 3 * FIN];
    __shared__ float bs[FOUT];
    for (int i = threadIdx.x; i < FOUT * 3 * FIN; i += 256) hs[i] = W[i];
    if (threadIdx.x < FOUT) bs[threadIdx.x] = bias[threadIdx.x];
    __syncthreads();

    const int nb = NN / 256;                 // 16
    const int b  = blockIdx.x / nb;
    const int n  = (blockIdx.x % nb) * 256 + threadIdx.x;

    float zv[3][FIN];
    const u16* zp0 = z0 + (size_t)b * FIN * NN + n;
    const u16* zp1 = z1 + (size_t)b * FIN * NN + n;
    const u16* zp2 = part2 + (size_t)b * FIN * NN + n;
#pragma unroll
    for (int f = 0; f < FIN; ++f) {
        zv[0][f] = bf2f(zp0[(size_t)f * NN]);
        zv[1][f] = bf2f(zp1[(size_t)f * NN]);
        float s = 0.f;
#pragma unroll
        for (int p = 0; p < KS; ++p)
            s += bf2f(zp2[(size_t)p * planeElems + (size_t)f * NN]);
        zv[2][f] = s;
    }

    u16* op = out + (size_t)b * FOUT * NN + n;
    for (int g = 0; g < FOUT; ++g) {
        float acc = bs[g];
#pragma unroll
        for (int k = 0; k < 3; ++k)
#pragma unroll
            for (int f = 0; f < FIN; ++f)
                acc = fmaf(hs[(g * 3 + k) * FIN + f], zv[k][f], acc);
        op[(size_t)g * NN] = f2bf(fmaxf(acc, 0.f));
    }
}

// ---------------------------------------------------------------------------
// MLP layer 1, split-K: h1p[slice][b][j] = sum_{slice} y[b,i]*Wm1[j,i].
// ---------------------------------------------------------------------------
__global__ __launch_bounds__(256) void mlp1(const u16* __restrict__ y,
                                            const float* __restrict__ Wm1,
                                            float* __restrict__ h1p)
{
    const int j    = blockIdx.x;
    const int base = blockIdx.y * 8192;
    const int D    = 16 * NN;  // 65536

    float acc[BB];
#pragma unroll
    for (int b = 0; b < BB; ++b) acc[b] = 0.f;

    const float* wrow = Wm1 + (size_t)j * D + base;
    for (int idx = threadIdx.x * 8; idx < 8192; idx += 256 * 8) {
        float4 w0 = *(const float4*)(wrow + idx);
        float4 w1 = *(const float4*)(wrow + idx + 4);
#pragma unroll
        for (int b = 0; b < BB; ++b) {
            uint4 yv = *(const uint4*)(y + (size_t)b * D + base + idx);
            union { u32 i; float f; } c[8];
            c[0].i = yv.x << 16; c[1].i = yv.x & 0xFFFF0000u;
            c[2].i = yv.y << 16; c[3].i = yv.y & 0xFFFF0000u;
            c[4].i = yv.z << 16; c[5].i = yv.z & 0xFFFF0000u;
            c[6].i = yv.w << 16; c[7].i = yv.w & 0xFFFF0000u;
            acc[b] = fmaf(w0.x, c[0].f, acc[b]);
            acc[b] = fmaf(w0.y, c[1].f, acc[b]);
            acc[b] = fmaf(w0.z, c[2].f, acc[b]);
            acc[b] = fmaf(w0.w, c[3].f, acc[b]);
            acc[b] = fmaf(w1.x, c[4].f, acc[b]);
            acc[b] = fmaf(w1.y, c[5].f, acc[b]);
            acc[b] = fmaf(w1.z, c[6].f, acc[b]);
            acc[b] = fmaf(w1.w, c[7].f, acc[b]);
        }
    }

    __shared__ float red[BB][4];
    const int lane = threadIdx.x & 63;
    const int w    = threadIdx.x >> 6;
#pragma unroll
    for (int b = 0; b < BB; ++b) {
        float v = acc[b];
        for (int off = 32; off > 0; off >>= 1) v += __shfl_down(v, off, 64);
        if (lane == 0) red[b][w] = v;
    }
    __syncthreads();
    if (threadIdx.x < BB) {
        const int b = threadIdx.x;
        h1p[blockIdx.y * (BB * 64) + b * 64 + j] =
            red[b][0] + red[b][1] + red[b][2] + red[b][3];
    }
}

// ---------------------------------------------------------------------------
// MLP layer 2 (+ slice-sum + layer-1 bias/ReLU). 1 block, 64 lanes.
// ---------------------------------------------------------------------------
__global__ void mlp2(const float* __restrict__ h1p,
                     const float* __restrict__ bm1,
                     const float* __restrict__ Wm2,
                     const float* __restrict__ bm2, float* __restrict__ out)
{
    const int lane = threadIdx.x;  // 0..63
    const float w    = Wm2[lane];
    const float b1   = bm1[lane];
    const float bias = bm2[0];
    for (int b = 0; b < BB; ++b) {
        float h = 0.f;
#pragma unroll
        for (int p = 0; p < 8; ++p) h += h1p[p * (BB * 64) + b * 64 + lane];
        float v = fmaxf(h + b1, 0.f) * w;
        for (int off = 32; off > 0; off >>= 1) v += __shfl_down(v, off, 64);
        if (lane == 0) out[b] = v + bias;
    }
}

// ---------------------------------------------------------------------------
extern "C" void kernel_launch(void* const* d_in, const int* in_sizes, int n_in,
                              void* d_out, int out_size, void* d_ws, size_t ws_size,
                              hipStream_t stream)
{
    const float* x   = (const float*)d_in[0];   // [8,16,4096]
    const float* Sc  = (const float*)d_in[1];   // [1,4096,4096]
    const float* Sl  = (const float*)d_in[2];   // [1,4096,4096]
    const float* Wc1 = (const float*)d_in[3];
    const float* bc1 = (const float*)d_in[4];
    const float* Wc2 = (const float*)d_in[5];
    const float* bc2 = (const float*)d_in[6];
    const float* Wl1 = (const float*)d_in[7];
    const float* bl1 = (const float*)d_in[8];
    const float* Wl2 = (const float*)d_in[9];
    const float* bl2 = (const float*)d_in[10];
    const float* Wm1 = (const float*)d_in[11];  // [64,65536]
    const float* bm1 = (const float*)d_in[12];
    const float* Wm2 = (const float*)d_in[13];  // [1,64]
    const float* bm2 = (const float*)d_in[14];
    float* out = (float*)d_out;                 // [8,1] f32

    char* ws = (char*)d_ws;                      // proven >= 81.02 MB
    u16*   part = (u16*)(ws);                    // 8 MB partial planes
    u16*   zb1  = (u16*)(ws + (8u  << 20));      // 2 MB
    u16*   yPa  = (u16*)(ws + (12u << 20));      // 2 MB
    u16*   yPb  = (u16*)(ws + (14u << 20));      // 2 MB
    float* h1p  = (float*)(ws + (16u << 20));    // 16 KB (8 slices x 8 x 64)
    u16*   Scb  = (u16*)(ws + (17u << 20));      // 32 MB
    u16*   Slb  = Scb + (size_t)NN * NN;         // 32 MB  (total 81.02 MB)

    const dim3 blk(256);
    const dim3 gridCmb(BB * NN / 256);           // 128
    const dim3 g128(32, 1, 8);                   // M=128: 256 blocks, ITERS=8
    const dim3 g256(32, 2, 4);                   // M=256: 256 blocks, ITERS=16
    const int  pl128 = 128 * NN;                 // plane elems, M=128
    const int  pl256 = 256 * NN;                 // plane elems, M=256

    cvt_x<<<256, blk, 0, stream>>>(x, yPa);

    // Layer 1: clique, Fin=16 (M=128) -> Fout=32.  First pass over Sc reads
    // f32 and writes Scb (bf16) as byproduct.
    diffuse_cvtB<8><<<g128, blk, 0, stream>>>(yPa, Sc, part, Scb);
    reduce_part<8><<<256, blk, 0, stream>>>(part, pl128, zb1);
    diffuse<8><<<g128, blk, 0, stream>>>(zb1, Scb, part);
    combine_relu<16, 32, 8><<<gridCmb, blk, 0, stream>>>(yPa, zb1, part, pl128,
                                                         Wc1, bc1, yPb);
    // Layer 2: clique, Fin=32 (M=256) -> Fout=16
    diffuse<16><<<g256, blk, 0, stream>>>(yPb, Scb, part);
    reduce_part<4><<<512, blk, 0, stream>>>(part, pl256, zb1);
    diffuse<16><<<g256, blk, 0, stream>>>(zb1, Scb, part);
    combine_relu<32, 16, 4><<<gridCmb, blk, 0, stream>>>(yPb, zb1, part, pl256,
                                                         Wc2, bc2, yPa);
    // Layer 3: line, Fin=16 (M=128) -> Fout=32.  First pass over Sl reads
    // f32 and writes Slb (bf16) as byproduct.
    diffuse_cvtB<8><<<g128, blk, 0, stream>>>(yPa, Sl, part, Slb);
    reduce_part<8><<<256, blk, 0, stream>>>(part, pl128, zb1);
    diffuse<8><<<g128, blk, 0, stream>>>(zb1, Slb, part);
    combine_relu<16, 32, 8><<<gridCmb, blk, 0, stream>>>(yPa, zb1, part, pl128,
                                                         Wl1, bl1, yPb);
    // Layer 4: line, Fin=32 (M=256) -> Fout=16
    diffuse<16><<<g256, blk, 0, stream>>>(yPb, Slb, part);
    reduce_part<4><<<512, blk, 0, stream>>>(part, pl256, zb1);
    diffuse<16><<<g256, blk, 0, stream>>>(zb1, Slb, part);
    combine_relu<32, 16, 4><<<gridCmb, blk, 0, stream>>>(yPb, zb1, part, pl256,
                                                         Wl2, bl2, yPa);
    // MLP
    mlp1<<<dim3(64, 8), blk, 0, stream>>>(yPa, Wm1, h1p);
    mlp2<<<1, 64, 0, stream>>>(h1p, bm1, Wm2, bm2, out);
}